// Round 5
// baseline (901.652 us; speedup 1.0000x reference)
//
#include <hip/hip_runtime.h>

#define EDGES 200000
#define NATOMS 100000
#define NMOLS 2000
#define H 128
#define MAXNB 15
#define AFD 18
#define INFD 23
#define LROW 136  // LDS A-tile row stride (bf16): +8 pad, 16B-aligned rows, 2-way banks
#define QROW 136  // int8 table row stride BYTES: 128 payload + 4 bf16 per-32ch block scales

// Precision ledger (measured):
//  R2: e4m3 tables            -> err 448 (== e4m3 sat; messages exceed +-448)
//  R3: e5m2 tables M1-M5      -> err 1088
//  R4: e5m2 M3-M5, bf16 early -> err 1120  => placement irrelevant; format is the issue
//  => per-element rel err must drop ~5x: block-scaled int8 (err ~ blockmax/508).

typedef unsigned short bf16s;
typedef unsigned char u8;
typedef __attribute__((ext_vector_type(8))) short short8;
typedef __attribute__((ext_vector_type(4))) float f32x4;
typedef __attribute__((ext_vector_type(2))) float f32x2;

__device__ inline float bf2f(bf16s u) {
  union { unsigned int i; float f; } c; c.i = ((unsigned int)u) << 16; return c.f;
}
__device__ inline bf16s f2bf(float f) {
  union { float f; unsigned int i; } c; c.f = f;
  unsigned int lsb = (c.i >> 16) & 1u;
  c.i += 0x7fffu + lsb;              // round-to-nearest-even
  return (bf16s)(c.i >> 16);
}
__device__ inline f32x2 bfpair(unsigned int u) {
  union { unsigned int i; float f; } lo, hi;
  lo.i = u << 16; hi.i = u & 0xffff0000u;
  return (f32x2){lo.f, hi.f};
}
__device__ inline unsigned int pack2(f32x2 v) {
  return (unsigned int)f2bf(fmaxf(v.x, 0.f)) |
         ((unsigned int)f2bf(fmaxf(v.y, 0.f)) << 16);
}
__device__ inline void store4(bf16s* p, const float v[4]) {
  ushort4 t; t.x = f2bf(v[0]); t.y = f2bf(v[1]); t.z = f2bf(v[2]); t.w = f2bf(v[3]);
  *(ushort4*)p = t;
}

// ------- one-time: Wt[n][k] = bf16(W[k][n]) for W_h and W_o[AFD:,:] -------
__global__ __launch_bounds__(256) void k_wt(
    const float* __restrict__ Wh, const float* __restrict__ Wo,
    bf16s* __restrict__ wt_h, bf16s* __restrict__ wt_o) {
  const float* S = blockIdx.x ? (Wo + AFD * H) : Wh;
  bf16s* D = blockIdx.x ? wt_o : wt_h;
  for (int i = threadIdx.x; i < H * H; i += 256) {
    int k = i >> 7, n = i & 127;
    D[n * H + k] = f2bf(S[i]);
  }
}

// Two-pass MFMA epilogue: 16x128 @ 128x128 from wave-private LDS tile.
// OUT_Q=1: excess-128 int8 rows (QROW bytes) with 4 inline bf16 block scales.
template <int OUT_Q>
__device__ inline void mfma_two_pass(const bf16s* Aw, const bf16s* __restrict__ Wt,
                                     void* __restrict__ PoutV, int ebase, int lane) {
  const int mm = lane & 15;
  const int quad = lane >> 4;
  const bf16s* Wp = Wt + (size_t)mm * H + quad * 8;
  const int rbase = ebase + quad * 4;
  f32x4 acc[2][4];
#pragma unroll
  for (int h = 0; h < 2; ++h)
#pragma unroll
    for (int i = 0; i < 4; ++i) acc[h][i] = (f32x4){0.f, 0.f, 0.f, 0.f};
#pragma unroll
  for (int kk = 0; kk < 4; ++kk) {
    short8 af = *(const short8*)&Aw[mm * LROW + quad * 8 + kk * 32];
#pragma unroll
    for (int h = 0; h < 2; ++h)
#pragma unroll
      for (int nt = 0; nt < 4; ++nt) {
        short8 bfr = *(const short8*)(Wp + (size_t)((h * 4 + nt) * 16) * H + kk * 32);
        acc[h][nt] = __builtin_amdgcn_mfma_f32_16x16x32_bf16(af, bfr, acc[h][nt], 0, 0, 0);
      }
  }
  if constexpr (OUT_Q) {
    u8* P8 = (u8*)PoutV;
    // lane's channel c = (h*4+nt)*16+mm -> 32-ch block b = h*2 + (nt>>1)
    float m[4][4];  // [row i][block b] absmax
#pragma unroll
    for (int i = 0; i < 4; ++i)
#pragma unroll
      for (int b = 0; b < 4; ++b) m[i][b] = 0.f;
#pragma unroll
    for (int h = 0; h < 2; ++h)
#pragma unroll
      for (int nt = 0; nt < 4; ++nt) {
        const int b = h * 2 + (nt >> 1);
#pragma unroll
        for (int i = 0; i < 4; ++i) m[i][b] = fmaxf(m[i][b], fabsf(acc[h][nt][i]));
      }
#pragma unroll
    for (int w = 1; w < 16; w <<= 1)
#pragma unroll
      for (int i = 0; i < 4; ++i)
#pragma unroll
        for (int b = 0; b < 4; ++b)
          m[i][b] = fmaxf(m[i][b], __shfl_xor(m[i][b], w, 16));
    float rs[4][4];
#pragma unroll
    for (int i = 0; i < 4; ++i)
#pragma unroll
      for (int b = 0; b < 4; ++b) {
        bf16s sb = f2bf(m[i][b] * (1.f / 127.f));
        float sd = bf2f(sb);  // decode-exact scale
        rs[i][b] = sd > 0.f ? 1.f / sd : 0.f;
        if (mm == 0) *(bf16s*)&P8[(size_t)(rbase + i) * QROW + 128 + b * 2] = sb;
      }
#pragma unroll
    for (int h = 0; h < 2; ++h)
#pragma unroll
      for (int nt = 0; nt < 4; ++nt) {
        const int b = h * 2 + (nt >> 1);
#pragma unroll
        for (int i = 0; i < 4; ++i) {
          float q = fminf(fmaxf(acc[h][nt][i] * rs[i][b] + 128.5f, 0.f), 255.f);
          P8[(size_t)(rbase + i) * QROW + (h * 4 + nt) * 16 + mm] = (u8)(unsigned)q;
        }
      }
  } else {
    bf16s* Pout = (bf16s*)PoutV;
#pragma unroll
    for (int h = 0; h < 2; ++h)
#pragma unroll
      for (int nt = 0; nt < 4; ++nt)
#pragma unroll
        for (int i = 0; i < 4; ++i)
          Pout[(size_t)(rbase + i) * H + (h * 4 + nt) * 16 + mm] = f2bf(acc[h][nt][i]);
  }
}

// ---- binput = fbonds @ W_i (stored bf16); M1 = relu(binput) @ W_h (bf16) ----
__global__ __launch_bounds__(256) void k_binput_gemm(
    const float* __restrict__ fbonds, const float* __restrict__ Wi,
    const bf16s* __restrict__ wt_h, bf16s* __restrict__ binput,
    bf16s* __restrict__ P1) {
  __shared__ float Wl[INFD * H];
  __shared__ bf16s Am[4][16 * LROW];
  const int tid = threadIdx.x;
  for (int i = tid; i < INFD * H; i += 256) Wl[i] = Wi[i];
  __syncthreads();
  const int wave = tid >> 6;
  const int lane = tid & 63;
  bf16s* Aw = Am[wave];
  const int ebase = (blockIdx.x * 4 + wave) * 16;
  const int sub = lane >> 5;
  const int col = lane & 31;
  for (int r = 0; r < 8; ++r) {
    const int erow = r * 2 + sub;
    const int e = ebase + erow;
    const float* fb = &fbonds[(size_t)e * INFD];
    float acc[4] = {0.f, 0.f, 0.f, 0.f};
#pragma unroll
    for (int k = 0; k < INFD; ++k) {
      float f = fb[k];
      float4 w = *(const float4*)&Wl[k * H + col * 4];
      acc[0] = fmaf(f, w.x, acc[0]); acc[1] = fmaf(f, w.y, acc[1]);
      acc[2] = fmaf(f, w.z, acc[2]); acc[3] = fmaf(f, w.w, acc[3]);
    }
    store4(&binput[(size_t)e * H + col * 4], acc);
    ushort4 mq;
    mq.x = f2bf(fmaxf(acc[0], 0.f)); mq.y = f2bf(fmaxf(acc[1], 0.f));
    mq.z = f2bf(fmaxf(acc[2], 0.f)); mq.w = f2bf(fmaxf(acc[3], 0.f));
    *(ushort4*)&Aw[erow * LROW + col * 4] = mq;
  }
  asm volatile("s_waitcnt lgkmcnt(0)" ::: "memory");
  mfma_two_pass<0>(Aw, wt_h, P1, ebase, lane);
}

// ---- fused depth step: Pout = (relu(binput + sum_j P[bgraph[e][j]])) @ Wt ----
// TBL_Q: 0 = bf16 256B rows; 1 = excess-128 int8 QROW rows w/ inline scales.
// decode: acc_c = binput_c + sum_j s_j*u_jc - 128*sum_j s_j  (per-lane block).
template <int TBL_Q, int OUT_Q>
__global__ __launch_bounds__(128, 4) void k_fused(
    const int* __restrict__ bgraph, const void* __restrict__ Pv,
    const bf16s* __restrict__ binput, const bf16s* __restrict__ Wt,
    void* __restrict__ Pout) {
  __shared__ bf16s Am[2][16 * LROW];
  const int tid = threadIdx.x;
  const int wave = tid >> 6;
  const int lane = tid & 63;
  bf16s* Aw = Am[wave];
  const int ebase = (blockIdx.x * 2 + wave) * 16;

  const int sub = lane >> 4;   // 4 rows per iteration
  const int col = lane & 15;   // 16 lanes x 8 channels = 128 cols
#pragma unroll
  for (int it = 0; it < 4; ++it) {
    const int erow = it * 4 + sub;
    const int e = ebase + erow;
    int idx[MAXNB];
#pragma unroll
    for (int j = 0; j < MAXNB; ++j) idx[j] = bgraph[(size_t)e * MAXNB + j];

    uint4 bi = *(const uint4*)&binput[(size_t)e * H + col * 8];
    f32x2 acc0 = bfpair(bi.x), acc1 = bfpair(bi.y);
    f32x2 acc2 = bfpair(bi.z), acc3 = bfpair(bi.w);

    if constexpr (TBL_Q) {
      const u8* P = (const u8*)Pv;
      uint2 t[MAXNB];
      float s[MAXNB];
#pragma unroll
      for (int j = 0; j < MAXNB; ++j) {
        const u8* rp = P + (size_t)idx[j] * QROW;
        t[j] = *(const uint2*)(rp + col * 8);
        s[j] = bf2f(*(const bf16s*)(rp + 128 + (col >> 2) * 2));
      }
      float ssum = 0.f;
#pragma unroll
      for (int j = 0; j < MAXNB; ++j) ssum += s[j];
#pragma unroll
      for (int j = 0; j < MAXNB; ++j) {
        const unsigned x = t[j].x, y = t[j].y;
        const float sj = s[j];
        acc0.x = fmaf(sj, (float)(x & 0xffu), acc0.x);
        acc0.y = fmaf(sj, (float)((x >> 8) & 0xffu), acc0.y);
        acc1.x = fmaf(sj, (float)((x >> 16) & 0xffu), acc1.x);
        acc1.y = fmaf(sj, (float)(x >> 24), acc1.y);
        acc2.x = fmaf(sj, (float)(y & 0xffu), acc2.x);
        acc2.y = fmaf(sj, (float)((y >> 8) & 0xffu), acc2.y);
        acc3.x = fmaf(sj, (float)((y >> 16) & 0xffu), acc3.x);
        acc3.y = fmaf(sj, (float)(y >> 24), acc3.y);
      }
      const float off = 128.f * ssum;
      acc0.x -= off; acc0.y -= off; acc1.x -= off; acc1.y -= off;
      acc2.x -= off; acc2.y -= off; acc3.x -= off; acc3.y -= off;
    } else {
      const bf16s* P = (const bf16s*)Pv;
      uint4 t[MAXNB];
#pragma unroll
      for (int j = 0; j < MAXNB; ++j)
        t[j] = *(const uint4*)&P[(size_t)idx[j] * H + col * 8];
#pragma unroll
      for (int j = 0; j < MAXNB; ++j) {
        acc0 += bfpair(t[j].x); acc1 += bfpair(t[j].y);
        acc2 += bfpair(t[j].z); acc3 += bfpair(t[j].w);
      }
    }
    uint4 o;
    o.x = pack2(acc0); o.y = pack2(acc1); o.z = pack2(acc2); o.w = pack2(acc3);
    *(uint4*)&Aw[erow * LROW + col * 8] = o;
  }
  asm volatile("s_waitcnt lgkmcnt(0)" ::: "memory");
  mfma_two_pass<OUT_Q>(Aw, Wt, Pout, ebase, lane);
}

// atom_hiddens = relu(fatoms @ Wo[0:18] + sum_j msgWo[agraph[a][j]] + b_o)
// msgWo (last message table, M6) is bf16; atomh bf16 (halves pool read).
__global__ __launch_bounds__(256, 4) void k_atoms(
    const float* __restrict__ fatoms, const int* __restrict__ agraph,
    const bf16s* __restrict__ msgWo, const float* __restrict__ Wo,
    const float* __restrict__ bo, bf16s* __restrict__ atomh) {
  __shared__ float Wl[AFD * H];
  const int tid = threadIdx.x;
  for (int i = tid; i < AFD * H; i += 256) Wl[i] = Wo[i];
  __syncthreads();
  const int col = tid & 15;
  const int a = blockIdx.x * 16 + (tid >> 4);
  int idx[MAXNB];
#pragma unroll
  for (int j = 0; j < MAXNB; ++j) idx[j] = agraph[(size_t)a * MAXNB + j];
  uint4 t[MAXNB];
#pragma unroll
  for (int j = 0; j < MAXNB; ++j)
    t[j] = *(const uint4*)&msgWo[(size_t)idx[j] * H + col * 8];
  float4 b0 = ((const float4*)bo)[col * 2];
  float4 b1 = ((const float4*)bo)[col * 2 + 1];
  f32x2 acc0 = (f32x2){b0.x, b0.y}, acc1 = (f32x2){b0.z, b0.w};
  f32x2 acc2 = (f32x2){b1.x, b1.y}, acc3 = (f32x2){b1.z, b1.w};
#pragma unroll
  for (int k = 0; k < AFD; ++k) {
    float f = fatoms[(size_t)a * AFD + k];
    float4 w0 = *(const float4*)&Wl[k * H + col * 8];
    float4 w1 = *(const float4*)&Wl[k * H + col * 8 + 4];
    acc0.x = fmaf(f, w0.x, acc0.x); acc0.y = fmaf(f, w0.y, acc0.y);
    acc1.x = fmaf(f, w0.z, acc1.x); acc1.y = fmaf(f, w0.w, acc1.y);
    acc2.x = fmaf(f, w1.x, acc2.x); acc2.y = fmaf(f, w1.y, acc2.y);
    acc3.x = fmaf(f, w1.z, acc3.x); acc3.y = fmaf(f, w1.w, acc3.y);
  }
#pragma unroll
  for (int j = 0; j < MAXNB; ++j) {
    acc0 += bfpair(t[j].x); acc1 += bfpair(t[j].y);
    acc2 += bfpair(t[j].z); acc3 += bfpair(t[j].w);
  }
  uint4 o;
  o.x = pack2(acc0); o.y = pack2(acc1); o.z = pack2(acc2); o.w = pack2(acc3);
  *(uint4*)&atomh[(size_t)a * H + col * 8] = o;
}

// ---------------- segment mean pool (bf16 in, f32 out) ----------------
__global__ void k_pool(const bf16s* __restrict__ atomh,
                       const int* __restrict__ sstart, const int* __restrict__ slen,
                       float* __restrict__ out) {
  const int m = blockIdx.x;
  const int c = threadIdx.x;
  const int s = sstart[m];
  const int L = slen[m];
  float sum = 0.f;
  for (int i = 0; i < L; ++i) sum += bf2f(atomh[(size_t)(s + i) * H + c]);
  out[m * H + c] = sum / (float)L;
}

extern "C" void kernel_launch(void* const* d_in, const int* in_sizes, int n_in,
                              void* d_out, int out_size, void* d_ws, size_t ws_size,
                              hipStream_t stream) {
  const float* fatoms = (const float*)d_in[0];
  const float* fbonds = (const float*)d_in[1];
  const int* agraph = (const int*)d_in[2];
  const int* bgraph = (const int*)d_in[3];
  const int* sstart = (const int*)d_in[4];
  const int* slen = (const int*)d_in[5];
  const float* Wi = (const float*)d_in[6];
  const float* Wh = (const float*)d_in[7];
  const float* Wo = (const float*)d_in[8];
  const float* bo = (const float*)d_in[9];
  float* out = (float*)d_out;

  const size_t EH = (size_t)EDGES * H;
  // Workspace (153.6 MB), overlay schedule:
  //  [0,   51.2M) binput bf16           (dead after M6; atomh overlays head)
  //  [51.2,102.4) B1: M1 bf16           -> after M1 dead: Q1 (M3/M5 int8, 27.2M)
  //  [78.4,105.6) Q2: M4 int8           (tail overlaps dead-M2 head of BB)
  //  [102.4,153.6) BB: M2 bf16 -> M6 bf16
  char* W = (char*)d_ws;
  bf16s* binput = (bf16s*)W;
  bf16s* B1 = (bf16s*)(W + EH * 2);
  bf16s* BB = (bf16s*)(W + EH * 4);
  u8* Q1 = (u8*)(W + EH * 2);
  u8* Q2 = Q1 + (size_t)EDGES * QROW;
  bf16s* atomh = (bf16s*)W;
  bf16s* wt_h = (bf16s*)d_out;   // stashed in d_out; k_pool overwrites later
  bf16s* wt_o = wt_h + H * H;

  k_wt<<<2, 256, 0, stream>>>(Wh, Wo, wt_h, wt_o);
  k_binput_gemm<<<EDGES / 64, 256, 0, stream>>>(fbonds, Wi, wt_h, binput, B1); // M1
  k_fused<0, 0><<<EDGES / 32, 128, 0, stream>>>(bgraph, B1, binput, wt_h, BB); // M2 bf16
  k_fused<0, 1><<<EDGES / 32, 128, 0, stream>>>(bgraph, BB, binput, wt_h, Q1); // M3 q8
  k_fused<1, 1><<<EDGES / 32, 128, 0, stream>>>(bgraph, Q1, binput, wt_h, Q2); // M4 q8
  k_fused<1, 1><<<EDGES / 32, 128, 0, stream>>>(bgraph, Q2, binput, wt_h, Q1); // M5 q8
  k_fused<1, 0><<<EDGES / 32, 128, 0, stream>>>(bgraph, Q1, binput, wt_o, BB); // M6 bf16
  k_atoms<<<NATOMS / 16, 256, 0, stream>>>(fatoms, agraph, BB, Wo, bo, atomh);
  k_pool<<<NMOLS, H, 0, stream>>>(atomh, sstart, slen, out);
}

// Round 6
// 843.536 us; speedup vs baseline: 1.0689x; 1.0689x over previous
//
#include <hip/hip_runtime.h>

#define EDGES 200000
#define NATOMS 100000
#define NMOLS 2000
#define H 128
#define MAXNB 15
#define AFD 18
#define INFD 23
#define LROW 136  // LDS A-tile row stride (bf16): +8 pad, 16B-aligned rows, 2-way banks

// Precision ledger (measured):
//  R2: e4m3 tables            -> err 448 (== e4m3 sat; messages exceed +-448)
//  R3: e5m2 tables M1-M5      -> err 1088
//  R4: e5m2 M3-M5, bf16 early -> err 1120  => placement irrelevant; format is the issue
//  R5: int8 per-32ch block scales on M3-M5 -> PASS.  R6 keeps R5 numerics exactly.
// Mechanics ledger (measured):
//  R5: inline scales at row+128 (QROW=136) -> fused q8-out +17us epilogue cost,
//      q8-gather barely faster (46 VMEM/row-iter, misaligned rows).
//  R6: aligned [E][128] payload + separate [E][4] bf16 scale array (1.6MB, L2-hot).

typedef unsigned short bf16s;
typedef unsigned char u8;
typedef __attribute__((ext_vector_type(8))) short short8;
typedef __attribute__((ext_vector_type(4))) float f32x4;
typedef __attribute__((ext_vector_type(2))) float f32x2;

__device__ inline float bf2f(bf16s u) {
  union { unsigned int i; float f; } c; c.i = ((unsigned int)u) << 16; return c.f;
}
__device__ inline bf16s f2bf(float f) {
  union { float f; unsigned int i; } c; c.f = f;
  unsigned int lsb = (c.i >> 16) & 1u;
  c.i += 0x7fffu + lsb;              // round-to-nearest-even
  return (bf16s)(c.i >> 16);
}
__device__ inline f32x2 bfpair(unsigned int u) {
  union { unsigned int i; float f; } lo, hi;
  lo.i = u << 16; hi.i = u & 0xffff0000u;
  return (f32x2){lo.f, hi.f};
}
__device__ inline unsigned int pack2(f32x2 v) {
  return (unsigned int)f2bf(fmaxf(v.x, 0.f)) |
         ((unsigned int)f2bf(fmaxf(v.y, 0.f)) << 16);
}
__device__ inline void store4(bf16s* p, const float v[4]) {
  ushort4 t; t.x = f2bf(v[0]); t.y = f2bf(v[1]); t.z = f2bf(v[2]); t.w = f2bf(v[3]);
  *(ushort4*)p = t;
}

// ------- one-time: Wt[n][k] = bf16(W[k][n]) for W_h and W_o[AFD:,:] -------
__global__ __launch_bounds__(256) void k_wt(
    const float* __restrict__ Wh, const float* __restrict__ Wo,
    bf16s* __restrict__ wt_h, bf16s* __restrict__ wt_o) {
  const float* S = blockIdx.x ? (Wo + AFD * H) : Wh;
  bf16s* D = blockIdx.x ? wt_o : wt_h;
  for (int i = threadIdx.x; i < H * H; i += 256) {
    int k = i >> 7, n = i & 127;
    D[n * H + k] = f2bf(S[i]);
  }
}

// MFMA epilogue: 16x128 @ 128x128 from wave-private LDS tile.
// OUT_Q=1: excess-128 int8 payload rows [E][128] (aligned) + per-32ch bf16
// block scales in a separate [E][4] array (Sout).
template <int OUT_Q>
__device__ inline void mfma_epi(const bf16s* Aw, const bf16s* __restrict__ Wt,
                                void* __restrict__ PoutV, bf16s* __restrict__ Sout,
                                int ebase, int lane) {
  const int mm = lane & 15;
  const int quad = lane >> 4;
  const bf16s* Wp = Wt + (size_t)mm * H + quad * 8;
  const int rbase = ebase + quad * 4;
  f32x4 acc[2][4];
#pragma unroll
  for (int h = 0; h < 2; ++h)
#pragma unroll
    for (int i = 0; i < 4; ++i) acc[h][i] = (f32x4){0.f, 0.f, 0.f, 0.f};
#pragma unroll
  for (int kk = 0; kk < 4; ++kk) {
    short8 af = *(const short8*)&Aw[mm * LROW + quad * 8 + kk * 32];
#pragma unroll
    for (int h = 0; h < 2; ++h)
#pragma unroll
      for (int nt = 0; nt < 4; ++nt) {
        short8 bfr = *(const short8*)(Wp + (size_t)((h * 4 + nt) * 16) * H + kk * 32);
        acc[h][nt] = __builtin_amdgcn_mfma_f32_16x16x32_bf16(af, bfr, acc[h][nt], 0, 0, 0);
      }
  }
  if constexpr (OUT_Q) {
    u8* P8 = (u8*)PoutV;
    // lane's channel c = (h*4+nt)*16+mm -> 32-ch block b = h*2 + (nt>>1)
    float m[4][4];  // [row i][block b] absmax
#pragma unroll
    for (int i = 0; i < 4; ++i)
#pragma unroll
      for (int b = 0; b < 4; ++b) m[i][b] = 0.f;
#pragma unroll
    for (int h = 0; h < 2; ++h)
#pragma unroll
      for (int nt = 0; nt < 4; ++nt) {
        const int b = h * 2 + (nt >> 1);
#pragma unroll
        for (int i = 0; i < 4; ++i) m[i][b] = fmaxf(m[i][b], fabsf(acc[h][nt][i]));
      }
#pragma unroll
    for (int w = 1; w < 16; w <<= 1)
#pragma unroll
      for (int i = 0; i < 4; ++i)
#pragma unroll
        for (int b = 0; b < 4; ++b)
          m[i][b] = fmaxf(m[i][b], __shfl_xor(m[i][b], w, 16));
    float rs[4][4];
    unsigned short sbits[4][4];
#pragma unroll
    for (int i = 0; i < 4; ++i)
#pragma unroll
      for (int b = 0; b < 4; ++b) {
        bf16s sb = f2bf(m[i][b] * (1.f / 127.f));
        float sd = bf2f(sb);  // decode-exact scale
        rs[i][b] = sd > 0.f ? 1.f / sd : 0.f;
        sbits[i][b] = sb;
      }
    if (mm == 0) {
#pragma unroll
      for (int i = 0; i < 4; ++i) {
        ushort4 sv;
        sv.x = sbits[i][0]; sv.y = sbits[i][1];
        sv.z = sbits[i][2]; sv.w = sbits[i][3];
        *(ushort4*)&Sout[(size_t)(rbase + i) * 4] = sv;
      }
    }
#pragma unroll
    for (int h = 0; h < 2; ++h)
#pragma unroll
      for (int nt = 0; nt < 4; ++nt) {
        const int b = h * 2 + (nt >> 1);
#pragma unroll
        for (int i = 0; i < 4; ++i) {
          float q = fminf(fmaxf(acc[h][nt][i] * rs[i][b] + 128.5f, 0.f), 255.f);
          P8[(size_t)(rbase + i) * H + (h * 4 + nt) * 16 + mm] = (u8)(unsigned)q;
        }
      }
  } else {
    bf16s* Pout = (bf16s*)PoutV;
#pragma unroll
    for (int h = 0; h < 2; ++h)
#pragma unroll
      for (int nt = 0; nt < 4; ++nt)
#pragma unroll
        for (int i = 0; i < 4; ++i)
          Pout[(size_t)(rbase + i) * H + (h * 4 + nt) * 16 + mm] = f2bf(acc[h][nt][i]);
  }
}

// ---- binput = fbonds @ W_i (stored bf16); M1 = relu(binput) @ W_h (bf16) ----
__global__ __launch_bounds__(256) void k_binput_gemm(
    const float* __restrict__ fbonds, const float* __restrict__ Wi,
    const bf16s* __restrict__ wt_h, bf16s* __restrict__ binput,
    bf16s* __restrict__ P1) {
  __shared__ float Wl[INFD * H];
  __shared__ bf16s Am[4][16 * LROW];
  const int tid = threadIdx.x;
  for (int i = tid; i < INFD * H; i += 256) Wl[i] = Wi[i];
  __syncthreads();
  const int wave = tid >> 6;
  const int lane = tid & 63;
  bf16s* Aw = Am[wave];
  const int ebase = (blockIdx.x * 4 + wave) * 16;
  const int sub = lane >> 5;
  const int col = lane & 31;
  for (int r = 0; r < 8; ++r) {
    const int erow = r * 2 + sub;
    const int e = ebase + erow;
    const float* fb = &fbonds[(size_t)e * INFD];
    float acc[4] = {0.f, 0.f, 0.f, 0.f};
#pragma unroll
    for (int k = 0; k < INFD; ++k) {
      float f = fb[k];
      float4 w = *(const float4*)&Wl[k * H + col * 4];
      acc[0] = fmaf(f, w.x, acc[0]); acc[1] = fmaf(f, w.y, acc[1]);
      acc[2] = fmaf(f, w.z, acc[2]); acc[3] = fmaf(f, w.w, acc[3]);
    }
    store4(&binput[(size_t)e * H + col * 4], acc);
    ushort4 mq;
    mq.x = f2bf(fmaxf(acc[0], 0.f)); mq.y = f2bf(fmaxf(acc[1], 0.f));
    mq.z = f2bf(fmaxf(acc[2], 0.f)); mq.w = f2bf(fmaxf(acc[3], 0.f));
    *(ushort4*)&Aw[erow * LROW + col * 4] = mq;
  }
  asm volatile("s_waitcnt lgkmcnt(0)" ::: "memory");
  mfma_epi<0>(Aw, wt_h, P1, nullptr, ebase, lane);
}

// ---- fused depth step: Pout = (relu(binput + sum_j P[bgraph[e][j]])) @ Wt ----
// TBL_Q: 0 = bf16 256B rows; 1 = int8 [E][128] aligned payload + [E][4] scales.
// decode: acc_c = binput_c + sum_j s_j*u_jc - 128*sum_j s_j  (per-lane block).
template <int TBL_Q, int OUT_Q>
__global__ __launch_bounds__(128, 4) void k_fused(
    const int* __restrict__ bgraph, const void* __restrict__ Pv,
    const bf16s* __restrict__ Sin, const bf16s* __restrict__ binput,
    const bf16s* __restrict__ Wt, void* __restrict__ Pout,
    bf16s* __restrict__ Sout) {
  __shared__ bf16s Am[2][16 * LROW];
  const int tid = threadIdx.x;
  const int wave = tid >> 6;
  const int lane = tid & 63;
  bf16s* Aw = Am[wave];
  const int ebase = (blockIdx.x * 2 + wave) * 16;

  const int sub = lane >> 4;   // 4 rows per iteration
  const int col = lane & 15;   // 16 lanes x 8 channels = 128 cols
#pragma unroll
  for (int it = 0; it < 4; ++it) {
    const int erow = it * 4 + sub;
    const int e = ebase + erow;
    int idx[MAXNB];
#pragma unroll
    for (int j = 0; j < MAXNB; ++j) idx[j] = bgraph[(size_t)e * MAXNB + j];

    uint4 bi = *(const uint4*)&binput[(size_t)e * H + col * 8];
    f32x2 acc0 = bfpair(bi.x), acc1 = bfpair(bi.y);
    f32x2 acc2 = bfpair(bi.z), acc3 = bfpair(bi.w);

    if constexpr (TBL_Q) {
      const u8* P = (const u8*)Pv;
      uint2 t[MAXNB];
      float s[MAXNB];
#pragma unroll
      for (int j = 0; j < MAXNB; ++j) {
        t[j] = *(const uint2*)&P[(size_t)idx[j] * H + col * 8];
        s[j] = bf2f(Sin[(size_t)idx[j] * 4 + (col >> 2)]);
      }
      float ssum = 0.f;
#pragma unroll
      for (int j = 0; j < MAXNB; ++j) ssum += s[j];
#pragma unroll
      for (int j = 0; j < MAXNB; ++j) {
        const unsigned x = t[j].x, y = t[j].y;
        const float sj = s[j];
        acc0.x = fmaf(sj, (float)(x & 0xffu), acc0.x);
        acc0.y = fmaf(sj, (float)((x >> 8) & 0xffu), acc0.y);
        acc1.x = fmaf(sj, (float)((x >> 16) & 0xffu), acc1.x);
        acc1.y = fmaf(sj, (float)(x >> 24), acc1.y);
        acc2.x = fmaf(sj, (float)(y & 0xffu), acc2.x);
        acc2.y = fmaf(sj, (float)((y >> 8) & 0xffu), acc2.y);
        acc3.x = fmaf(sj, (float)((y >> 16) & 0xffu), acc3.x);
        acc3.y = fmaf(sj, (float)(y >> 24), acc3.y);
      }
      const float off = 128.f * ssum;
      acc0.x -= off; acc0.y -= off; acc1.x -= off; acc1.y -= off;
      acc2.x -= off; acc2.y -= off; acc3.x -= off; acc3.y -= off;
    } else {
      const bf16s* P = (const bf16s*)Pv;
      uint4 t[MAXNB];
#pragma unroll
      for (int j = 0; j < MAXNB; ++j)
        t[j] = *(const uint4*)&P[(size_t)idx[j] * H + col * 8];
#pragma unroll
      for (int j = 0; j < MAXNB; ++j) {
        acc0 += bfpair(t[j].x); acc1 += bfpair(t[j].y);
        acc2 += bfpair(t[j].z); acc3 += bfpair(t[j].w);
      }
    }
    uint4 o;
    o.x = pack2(acc0); o.y = pack2(acc1); o.z = pack2(acc2); o.w = pack2(acc3);
    *(uint4*)&Aw[erow * LROW + col * 8] = o;
  }
  asm volatile("s_waitcnt lgkmcnt(0)" ::: "memory");
  mfma_epi<OUT_Q>(Aw, Wt, Pout, Sout, ebase, lane);
}

// atom_hiddens = relu(fatoms @ Wo[0:18] + sum_j msgWo[agraph[a][j]] + b_o)
// msgWo (last message table, M6) is bf16; atomh bf16 (halves pool read).
__global__ __launch_bounds__(256, 4) void k_atoms(
    const float* __restrict__ fatoms, const int* __restrict__ agraph,
    const bf16s* __restrict__ msgWo, const float* __restrict__ Wo,
    const float* __restrict__ bo, bf16s* __restrict__ atomh) {
  __shared__ float Wl[AFD * H];
  const int tid = threadIdx.x;
  for (int i = tid; i < AFD * H; i += 256) Wl[i] = Wo[i];
  __syncthreads();
  const int col = tid & 15;
  const int a = blockIdx.x * 16 + (tid >> 4);
  int idx[MAXNB];
#pragma unroll
  for (int j = 0; j < MAXNB; ++j) idx[j] = agraph[(size_t)a * MAXNB + j];
  uint4 t[MAXNB];
#pragma unroll
  for (int j = 0; j < MAXNB; ++j)
    t[j] = *(const uint4*)&msgWo[(size_t)idx[j] * H + col * 8];
  float4 b0 = ((const float4*)bo)[col * 2];
  float4 b1 = ((const float4*)bo)[col * 2 + 1];
  f32x2 acc0 = (f32x2){b0.x, b0.y}, acc1 = (f32x2){b0.z, b0.w};
  f32x2 acc2 = (f32x2){b1.x, b1.y}, acc3 = (f32x2){b1.z, b1.w};
#pragma unroll
  for (int k = 0; k < AFD; ++k) {
    float f = fatoms[(size_t)a * AFD + k];
    float4 w0 = *(const float4*)&Wl[k * H + col * 8];
    float4 w1 = *(const float4*)&Wl[k * H + col * 8 + 4];
    acc0.x = fmaf(f, w0.x, acc0.x); acc0.y = fmaf(f, w0.y, acc0.y);
    acc1.x = fmaf(f, w0.z, acc1.x); acc1.y = fmaf(f, w0.w, acc1.y);
    acc2.x = fmaf(f, w1.x, acc2.x); acc2.y = fmaf(f, w1.y, acc2.y);
    acc3.x = fmaf(f, w1.z, acc3.x); acc3.y = fmaf(f, w1.w, acc3.y);
  }
#pragma unroll
  for (int j = 0; j < MAXNB; ++j) {
    acc0 += bfpair(t[j].x); acc1 += bfpair(t[j].y);
    acc2 += bfpair(t[j].z); acc3 += bfpair(t[j].w);
  }
  uint4 o;
  o.x = pack2(acc0); o.y = pack2(acc1); o.z = pack2(acc2); o.w = pack2(acc3);
  *(uint4*)&atomh[(size_t)a * H + col * 8] = o;
}

// ---------------- segment mean pool (bf16 in, f32 out) ----------------
__global__ void k_pool(const bf16s* __restrict__ atomh,
                       const int* __restrict__ sstart, const int* __restrict__ slen,
                       float* __restrict__ out) {
  const int m = blockIdx.x;
  const int c = threadIdx.x;
  const int s = sstart[m];
  const int L = slen[m];
  float sum = 0.f;
  for (int i = 0; i < L; ++i) sum += bf2f(atomh[(size_t)(s + i) * H + c]);
  out[m * H + c] = sum / (float)L;
}

extern "C" void kernel_launch(void* const* d_in, const int* in_sizes, int n_in,
                              void* d_out, int out_size, void* d_ws, size_t ws_size,
                              hipStream_t stream) {
  const float* fatoms = (const float*)d_in[0];
  const float* fbonds = (const float*)d_in[1];
  const int* agraph = (const int*)d_in[2];
  const int* bgraph = (const int*)d_in[3];
  const int* sstart = (const int*)d_in[4];
  const int* slen = (const int*)d_in[5];
  const float* Wi = (const float*)d_in[6];
  const float* Wh = (const float*)d_in[7];
  const float* Wo = (const float*)d_in[8];
  const float* bo = (const float*)d_in[9];
  float* out = (float*)d_out;

  const size_t EH = (size_t)EDGES * H;   // 25.6M elements
  // Workspace (153.6 MB), byte offsets; overlay schedule:
  //  [0,      2EH) binput bf16 51.2MB     (dead after M6; atomh overlays)
  //  [2EH,    4EH) B1 region: M1 bf16  -> after M2: QA[E][128] at 2EH (25.6MB)
  //                                        + SA[E][4] bf16 at 3EH (1.6MB)
  //  [4EH,    6EH) BB region: M2 bf16  -> after M3: QB at 4EH + SB at 5EH
  //                                     -> M6 bf16 at 4EH (QB/SB dead)
  char* W = (char*)d_ws;
  bf16s* binput = (bf16s*)W;
  bf16s* B1 = (bf16s*)(W + 2 * EH);
  bf16s* BB = (bf16s*)(W + 4 * EH);
  u8*    QA = (u8*)(W + 2 * EH);
  bf16s* SA = (bf16s*)(W + 3 * EH);
  u8*    QB = (u8*)(W + 4 * EH);
  bf16s* SB = (bf16s*)(W + 5 * EH);
  bf16s* atomh = (bf16s*)W;
  bf16s* wt_h = (bf16s*)d_out;   // stashed in d_out; k_pool overwrites later
  bf16s* wt_o = wt_h + H * H;

  k_wt<<<2, 256, 0, stream>>>(Wh, Wo, wt_h, wt_o);
  k_binput_gemm<<<EDGES / 64, 256, 0, stream>>>(fbonds, Wi, wt_h, binput, B1);           // M1
  k_fused<0, 0><<<EDGES / 32, 128, 0, stream>>>(bgraph, B1, nullptr, binput, wt_h, BB, nullptr); // M2 bf16
  k_fused<0, 1><<<EDGES / 32, 128, 0, stream>>>(bgraph, BB, nullptr, binput, wt_h, QA, SA);      // M3 q8
  k_fused<1, 1><<<EDGES / 32, 128, 0, stream>>>(bgraph, QA, SA, binput, wt_h, QB, SB);           // M4 q8
  k_fused<1, 1><<<EDGES / 32, 128, 0, stream>>>(bgraph, QB, SB, binput, wt_h, QA, SA);           // M5 q8
  k_fused<1, 0><<<EDGES / 32, 128, 0, stream>>>(bgraph, QA, SA, binput, wt_o, BB, nullptr);      // M6 bf16
  k_atoms<<<NATOMS / 16, 256, 0, stream>>>(fatoms, agraph, BB, Wo, bo, atomh);
  k_pool<<<NMOLS, H, 0, stream>>>(atomh, sstart, slen, out);
}

// Round 7
// 801.338 us; speedup vs baseline: 1.1252x; 1.0527x over previous
//
#include <hip/hip_runtime.h>

#define EDGES 200000
#define NATOMS 100000
#define NMOLS 2000
#define H 128
#define MAXNB 15
#define AFD 18
#define INFD 23
#define LROW 136  // LDS A-tile row stride (bf16): +8 pad, 16B-aligned rows, 2-way banks

// Precision ledger (measured):
//  R2: e4m3 tables            -> err 448 (== e4m3 sat; messages exceed +-448)
//  R3: e5m2 tables M1-M5      -> err 1088
//  R4: e5m2 M3-M5 + e4m3 binput -> err 1120 (=> binput e4m3 contribution <= ~32)
//  R5/R6: int8 per-32ch block scales on M3-M5 -> PASS (error margin unknown)
//  R7: + e4m3 binput (bounded by R4 delta) + q8 M6 (amplification-1 injection).
//      M1/M2 tables stay bf16 (recursive injections; margin protection).
// Mechanics ledger (measured):
//  R5: inline scales at row+128 -> q8-out epilogue +17us; misaligned rows.
//  R6: aligned [E][128] payload + [E][4] scales -> q8 GATHER fixed (~103us),
//      epilogue still +17us -> R7 moves absmax reduce from shfl (ds_swizzle,
//      LDS pipe) to DPP row_ror max (VALU pipe), bit-identical.

typedef unsigned short bf16s;
typedef unsigned char u8;
typedef __attribute__((ext_vector_type(8))) short short8;
typedef __attribute__((ext_vector_type(4))) float f32x4;
typedef __attribute__((ext_vector_type(2))) float f32x2;

__device__ inline float bf2f(bf16s u) {
  union { unsigned int i; float f; } c; c.i = ((unsigned int)u) << 16; return c.f;
}
__device__ inline bf16s f2bf(float f) {
  union { float f; unsigned int i; } c; c.f = f;
  unsigned int lsb = (c.i >> 16) & 1u;
  c.i += 0x7fffu + lsb;              // round-to-nearest-even
  return (bf16s)(c.i >> 16);
}
__device__ inline f32x2 bfpair(unsigned int u) {
  union { unsigned int i; float f; } lo, hi;
  lo.i = u << 16; hi.i = u & 0xffff0000u;
  return (f32x2){lo.f, hi.f};
}
__device__ inline unsigned int pack2(f32x2 v) {
  return (unsigned int)f2bf(fmaxf(v.x, 0.f)) |
         ((unsigned int)f2bf(fmaxf(v.y, 0.f)) << 16);
}
// pack 4 f32 into 4 e4m3 bytes (one dword)
__device__ inline unsigned int pack4_fp8(float a, float b, float c, float d) {
  int lo = __builtin_amdgcn_cvt_pk_fp8_f32(a, b, 0, false);
  int full = __builtin_amdgcn_cvt_pk_fp8_f32(c, d, lo, true);
  return (unsigned int)full;
}
// 16-lane max reduce on the VALU pipe via DPP row rotations (ror 1,2,4,8).
// Bit-identical to a shfl_xor butterfly (same 16 values, fmax assoc/comm).
#define DPPMAX_STEP(m, CTRL)                                                   \
  {                                                                            \
    int _t = __builtin_amdgcn_update_dpp(                                      \
        0, __builtin_bit_cast(int, m), CTRL, 0xf, 0xf, false);                 \
    m = fmaxf(m, __builtin_bit_cast(float, _t));                               \
  }
__device__ inline float dpp_max16(float m) {
  DPPMAX_STEP(m, 0x121);  // row_ror:1
  DPPMAX_STEP(m, 0x122);  // row_ror:2
  DPPMAX_STEP(m, 0x124);  // row_ror:4
  DPPMAX_STEP(m, 0x128);  // row_ror:8
  return m;
}

// ------- one-time: Wt[n][k] = bf16(W[k][n]) for W_h and W_o[AFD:,:] -------
__global__ __launch_bounds__(256) void k_wt(
    const float* __restrict__ Wh, const float* __restrict__ Wo,
    bf16s* __restrict__ wt_h, bf16s* __restrict__ wt_o) {
  const float* S = blockIdx.x ? (Wo + AFD * H) : Wh;
  bf16s* D = blockIdx.x ? wt_o : wt_h;
  for (int i = threadIdx.x; i < H * H; i += 256) {
    int k = i >> 7, n = i & 127;
    D[n * H + k] = f2bf(S[i]);
  }
}

// MFMA epilogue: 16x128 @ 128x128 from wave-private LDS tile.
// OUT_Q=1: excess-128 int8 payload rows [E][128] (aligned) + per-32ch bf16
// block scales in a separate [E][4] array (Sout).
template <int OUT_Q>
__device__ inline void mfma_epi(const bf16s* Aw, const bf16s* __restrict__ Wt,
                                void* __restrict__ PoutV, bf16s* __restrict__ Sout,
                                int ebase, int lane) {
  const int mm = lane & 15;
  const int quad = lane >> 4;
  const bf16s* Wp = Wt + (size_t)mm * H + quad * 8;
  const int rbase = ebase + quad * 4;
  f32x4 acc[2][4];
#pragma unroll
  for (int h = 0; h < 2; ++h)
#pragma unroll
    for (int i = 0; i < 4; ++i) acc[h][i] = (f32x4){0.f, 0.f, 0.f, 0.f};
#pragma unroll
  for (int kk = 0; kk < 4; ++kk) {
    short8 af = *(const short8*)&Aw[mm * LROW + quad * 8 + kk * 32];
#pragma unroll
    for (int h = 0; h < 2; ++h)
#pragma unroll
      for (int nt = 0; nt < 4; ++nt) {
        short8 bfr = *(const short8*)(Wp + (size_t)((h * 4 + nt) * 16) * H + kk * 32);
        acc[h][nt] = __builtin_amdgcn_mfma_f32_16x16x32_bf16(af, bfr, acc[h][nt], 0, 0, 0);
      }
  }
  if constexpr (OUT_Q) {
    u8* P8 = (u8*)PoutV;
    // lane's channel c = (h*4+nt)*16+mm -> 32-ch block b = h*2 + (nt>>1)
    float m[4][4];  // [row i][block b] absmax
#pragma unroll
    for (int i = 0; i < 4; ++i)
#pragma unroll
      for (int b = 0; b < 4; ++b) m[i][b] = 0.f;
#pragma unroll
    for (int h = 0; h < 2; ++h)
#pragma unroll
      for (int nt = 0; nt < 4; ++nt) {
        const int b = h * 2 + (nt >> 1);
#pragma unroll
        for (int i = 0; i < 4; ++i) m[i][b] = fmaxf(m[i][b], fabsf(acc[h][nt][i]));
      }
#pragma unroll
    for (int i = 0; i < 4; ++i)
#pragma unroll
      for (int b = 0; b < 4; ++b) m[i][b] = dpp_max16(m[i][b]);
    float rs[4][4];
    unsigned short sbits[4][4];
#pragma unroll
    for (int i = 0; i < 4; ++i)
#pragma unroll
      for (int b = 0; b < 4; ++b) {
        bf16s sb = f2bf(m[i][b] * (1.f / 127.f));
        float sd = bf2f(sb);  // decode-exact scale
        rs[i][b] = sd > 0.f ? 1.f / sd : 0.f;
        sbits[i][b] = sb;
      }
    if (mm == 0) {
#pragma unroll
      for (int i = 0; i < 4; ++i) {
        ushort4 sv;
        sv.x = sbits[i][0]; sv.y = sbits[i][1];
        sv.z = sbits[i][2]; sv.w = sbits[i][3];
        *(ushort4*)&Sout[(size_t)(rbase + i) * 4] = sv;
      }
    }
#pragma unroll
    for (int h = 0; h < 2; ++h)
#pragma unroll
      for (int nt = 0; nt < 4; ++nt) {
        const int b = h * 2 + (nt >> 1);
#pragma unroll
        for (int i = 0; i < 4; ++i) {
          float q = fminf(fmaxf(acc[h][nt][i] * rs[i][b] + 128.5f, 0.f), 255.f);
          P8[(size_t)(rbase + i) * H + (h * 4 + nt) * 16 + mm] = (u8)(unsigned)q;
        }
      }
  } else {
    bf16s* Pout = (bf16s*)PoutV;
#pragma unroll
    for (int h = 0; h < 2; ++h)
#pragma unroll
      for (int nt = 0; nt < 4; ++nt)
#pragma unroll
        for (int i = 0; i < 4; ++i)
          Pout[(size_t)(rbase + i) * H + (h * 4 + nt) * 16 + mm] = f2bf(acc[h][nt][i]);
  }
}

// ---- binput = fbonds @ W_i (stored e4m3); M1 = relu(binput) @ W_h (bf16) ----
// binput e4m3 is range-safe (values O(+-1.5) << 448) and its error
// contribution is bounded by the R4-R3 delta (~+32 on a 268.8 budget).
__global__ __launch_bounds__(256) void k_binput_gemm(
    const float* __restrict__ fbonds, const float* __restrict__ Wi,
    const bf16s* __restrict__ wt_h, u8* __restrict__ binput8,
    bf16s* __restrict__ P1) {
  __shared__ float Wl[INFD * H];
  __shared__ bf16s Am[4][16 * LROW];
  const int tid = threadIdx.x;
  for (int i = tid; i < INFD * H; i += 256) Wl[i] = Wi[i];
  __syncthreads();
  const int wave = tid >> 6;
  const int lane = tid & 63;
  bf16s* Aw = Am[wave];
  const int ebase = (blockIdx.x * 4 + wave) * 16;
  const int sub = lane >> 5;
  const int col = lane & 31;
  for (int r = 0; r < 8; ++r) {
    const int erow = r * 2 + sub;
    const int e = ebase + erow;
    const float* fb = &fbonds[(size_t)e * INFD];
    float acc[4] = {0.f, 0.f, 0.f, 0.f};
#pragma unroll
    for (int k = 0; k < INFD; ++k) {
      float f = fb[k];
      float4 w = *(const float4*)&Wl[k * H + col * 4];
      acc[0] = fmaf(f, w.x, acc[0]); acc[1] = fmaf(f, w.y, acc[1]);
      acc[2] = fmaf(f, w.z, acc[2]); acc[3] = fmaf(f, w.w, acc[3]);
    }
    *(unsigned int*)&binput8[(size_t)e * H + col * 4] =
        pack4_fp8(acc[0], acc[1], acc[2], acc[3]);
    ushort4 mq;
    mq.x = f2bf(fmaxf(acc[0], 0.f)); mq.y = f2bf(fmaxf(acc[1], 0.f));
    mq.z = f2bf(fmaxf(acc[2], 0.f)); mq.w = f2bf(fmaxf(acc[3], 0.f));
    *(ushort4*)&Aw[erow * LROW + col * 4] = mq;
  }
  asm volatile("s_waitcnt lgkmcnt(0)" ::: "memory");
  mfma_epi<0>(Aw, wt_h, P1, nullptr, ebase, lane);
}

// ---- fused depth step: Pout = (relu(binput + sum_j P[bgraph[e][j]])) @ Wt ----
// TBL_Q: 0 = bf16 256B rows; 1 = int8 [E][128] aligned payload + [E][4] scales.
// decode: acc_c = binput_c + sum_j s_j*u_jc - 128*sum_j s_j  (per-lane block).
template <int TBL_Q, int OUT_Q>
__global__ __launch_bounds__(128, 4) void k_fused(
    const int* __restrict__ bgraph, const void* __restrict__ Pv,
    const bf16s* __restrict__ Sin, const u8* __restrict__ binput8,
    const bf16s* __restrict__ Wt, void* __restrict__ Pout,
    bf16s* __restrict__ Sout) {
  __shared__ bf16s Am[2][16 * LROW];
  const int tid = threadIdx.x;
  const int wave = tid >> 6;
  const int lane = tid & 63;
  bf16s* Aw = Am[wave];
  const int ebase = (blockIdx.x * 2 + wave) * 16;

  const int sub = lane >> 4;   // 4 rows per iteration
  const int col = lane & 15;   // 16 lanes x 8 channels = 128 cols
#pragma unroll
  for (int it = 0; it < 4; ++it) {
    const int erow = it * 4 + sub;
    const int e = ebase + erow;
    int idx[MAXNB];
#pragma unroll
    for (int j = 0; j < MAXNB; ++j) idx[j] = bgraph[(size_t)e * MAXNB + j];

    uint2 bi = *(const uint2*)&binput8[(size_t)e * H + col * 8];
    f32x2 acc0 = __builtin_amdgcn_cvt_pk_f32_fp8(bi.x, false);
    f32x2 acc1 = __builtin_amdgcn_cvt_pk_f32_fp8(bi.x, true);
    f32x2 acc2 = __builtin_amdgcn_cvt_pk_f32_fp8(bi.y, false);
    f32x2 acc3 = __builtin_amdgcn_cvt_pk_f32_fp8(bi.y, true);

    if constexpr (TBL_Q) {
      const u8* P = (const u8*)Pv;
      uint2 t[MAXNB];
      float s[MAXNB];
#pragma unroll
      for (int j = 0; j < MAXNB; ++j) {
        t[j] = *(const uint2*)&P[(size_t)idx[j] * H + col * 8];
        s[j] = bf2f(Sin[(size_t)idx[j] * 4 + (col >> 2)]);
      }
      float ssum = 0.f;
#pragma unroll
      for (int j = 0; j < MAXNB; ++j) ssum += s[j];
#pragma unroll
      for (int j = 0; j < MAXNB; ++j) {
        const unsigned x = t[j].x, y = t[j].y;
        const float sj = s[j];
        acc0.x = fmaf(sj, (float)(x & 0xffu), acc0.x);
        acc0.y = fmaf(sj, (float)((x >> 8) & 0xffu), acc0.y);
        acc1.x = fmaf(sj, (float)((x >> 16) & 0xffu), acc1.x);
        acc1.y = fmaf(sj, (float)(x >> 24), acc1.y);
        acc2.x = fmaf(sj, (float)(y & 0xffu), acc2.x);
        acc2.y = fmaf(sj, (float)((y >> 8) & 0xffu), acc2.y);
        acc3.x = fmaf(sj, (float)((y >> 16) & 0xffu), acc3.x);
        acc3.y = fmaf(sj, (float)(y >> 24), acc3.y);
      }
      const float off = 128.f * ssum;
      acc0.x -= off; acc0.y -= off; acc1.x -= off; acc1.y -= off;
      acc2.x -= off; acc2.y -= off; acc3.x -= off; acc3.y -= off;
    } else {
      const bf16s* P = (const bf16s*)Pv;
      uint4 t[MAXNB];
#pragma unroll
      for (int j = 0; j < MAXNB; ++j)
        t[j] = *(const uint4*)&P[(size_t)idx[j] * H + col * 8];
#pragma unroll
      for (int j = 0; j < MAXNB; ++j) {
        acc0 += bfpair(t[j].x); acc1 += bfpair(t[j].y);
        acc2 += bfpair(t[j].z); acc3 += bfpair(t[j].w);
      }
    }
    uint4 o;
    o.x = pack2(acc0); o.y = pack2(acc1); o.z = pack2(acc2); o.w = pack2(acc3);
    *(uint4*)&Aw[erow * LROW + col * 8] = o;
  }
  asm volatile("s_waitcnt lgkmcnt(0)" ::: "memory");
  mfma_epi<OUT_Q>(Aw, Wt, Pout, Sout, ebase, lane);
}

// atom_hiddens = relu(fatoms @ Wo[0:18] + sum_j msg[agraph[a][j]] + b_o)
// M6 table is q8 (amplification-1 injection: error passes through W_o only).
__global__ __launch_bounds__(256, 4) void k_atoms(
    const float* __restrict__ fatoms, const int* __restrict__ agraph,
    const u8* __restrict__ msgQ, const bf16s* __restrict__ msgS,
    const float* __restrict__ Wo, const float* __restrict__ bo,
    bf16s* __restrict__ atomh) {
  __shared__ float Wl[AFD * H];
  const int tid = threadIdx.x;
  for (int i = tid; i < AFD * H; i += 256) Wl[i] = Wo[i];
  __syncthreads();
  const int col = tid & 15;
  const int a = blockIdx.x * 16 + (tid >> 4);
  int idx[MAXNB];
#pragma unroll
  for (int j = 0; j < MAXNB; ++j) idx[j] = agraph[(size_t)a * MAXNB + j];
  uint2 t[MAXNB];
  float s[MAXNB];
#pragma unroll
  for (int j = 0; j < MAXNB; ++j) {
    t[j] = *(const uint2*)&msgQ[(size_t)idx[j] * H + col * 8];
    s[j] = bf2f(msgS[(size_t)idx[j] * 4 + (col >> 2)]);
  }
  float4 b0 = ((const float4*)bo)[col * 2];
  float4 b1 = ((const float4*)bo)[col * 2 + 1];
  f32x2 acc0 = (f32x2){b0.x, b0.y}, acc1 = (f32x2){b0.z, b0.w};
  f32x2 acc2 = (f32x2){b1.x, b1.y}, acc3 = (f32x2){b1.z, b1.w};
#pragma unroll
  for (int k = 0; k < AFD; ++k) {
    float f = fatoms[(size_t)a * AFD + k];
    float4 w0 = *(const float4*)&Wl[k * H + col * 8];
    float4 w1 = *(const float4*)&Wl[k * H + col * 8 + 4];
    acc0.x = fmaf(f, w0.x, acc0.x); acc0.y = fmaf(f, w0.y, acc0.y);
    acc1.x = fmaf(f, w0.z, acc1.x); acc1.y = fmaf(f, w0.w, acc1.y);
    acc2.x = fmaf(f, w1.x, acc2.x); acc2.y = fmaf(f, w1.y, acc2.y);
    acc3.x = fmaf(f, w1.z, acc3.x); acc3.y = fmaf(f, w1.w, acc3.y);
  }
  float ssum = 0.f;
#pragma unroll
  for (int j = 0; j < MAXNB; ++j) ssum += s[j];
#pragma unroll
  for (int j = 0; j < MAXNB; ++j) {
    const unsigned x = t[j].x, y = t[j].y;
    const float sj = s[j];
    acc0.x = fmaf(sj, (float)(x & 0xffu), acc0.x);
    acc0.y = fmaf(sj, (float)((x >> 8) & 0xffu), acc0.y);
    acc1.x = fmaf(sj, (float)((x >> 16) & 0xffu), acc1.x);
    acc1.y = fmaf(sj, (float)(x >> 24), acc1.y);
    acc2.x = fmaf(sj, (float)(y & 0xffu), acc2.x);
    acc2.y = fmaf(sj, (float)((y >> 8) & 0xffu), acc2.y);
    acc3.x = fmaf(sj, (float)((y >> 16) & 0xffu), acc3.x);
    acc3.y = fmaf(sj, (float)(y >> 24), acc3.y);
  }
  const float off = 128.f * ssum;
  acc0.x -= off; acc0.y -= off; acc1.x -= off; acc1.y -= off;
  acc2.x -= off; acc2.y -= off; acc3.x -= off; acc3.y -= off;
  uint4 o;
  o.x = pack2(acc0); o.y = pack2(acc1); o.z = pack2(acc2); o.w = pack2(acc3);
  *(uint4*)&atomh[(size_t)a * H + col * 8] = o;
}

// ---------------- segment mean pool (bf16 in, f32 out) ----------------
__global__ void k_pool(const bf16s* __restrict__ atomh,
                       const int* __restrict__ sstart, const int* __restrict__ slen,
                       float* __restrict__ out) {
  const int m = blockIdx.x;
  const int c = threadIdx.x;
  const int s = sstart[m];
  const int L = slen[m];
  float sum = 0.f;
  for (int i = 0; i < L; ++i) sum += bf2f(atomh[(size_t)(s + i) * H + c]);
  out[m * H + c] = sum / (float)L;
}

extern "C" void kernel_launch(void* const* d_in, const int* in_sizes, int n_in,
                              void* d_out, int out_size, void* d_ws, size_t ws_size,
                              hipStream_t stream) {
  const float* fatoms = (const float*)d_in[0];
  const float* fbonds = (const float*)d_in[1];
  const int* agraph = (const int*)d_in[2];
  const int* bgraph = (const int*)d_in[3];
  const int* sstart = (const int*)d_in[4];
  const int* slen = (const int*)d_in[5];
  const float* Wi = (const float*)d_in[6];
  const float* Wh = (const float*)d_in[7];
  const float* Wo = (const float*)d_in[8];
  const float* bo = (const float*)d_in[9];
  float* out = (float*)d_out;

  const size_t EH = (size_t)EDGES * H;   // 25.6M elements
  // Workspace (153.6 MB), byte offsets; overlay schedule:
  //  [0,      EH) binput8 e4m3 25.6MB   (dead after M6; atomh overlays)
  //  [2EH,   4EH) B1: M1 bf16          -> after M3: QA[E][128] + SA[E][4]
  //  [4EH,   6EH) BB: M2 bf16          -> after M4: QB[E][128] + SB[E][4]
  //                                       M6 q8 lands in QB/SB (dead M4 data)
  char* W = (char*)d_ws;
  u8*    binput8 = (u8*)W;
  bf16s* B1 = (bf16s*)(W + 2 * EH);
  bf16s* BB = (bf16s*)(W + 4 * EH);
  u8*    QA = (u8*)(W + 2 * EH);
  bf16s* SA = (bf16s*)(W + 3 * EH);
  u8*    QB = (u8*)(W + 4 * EH);
  bf16s* SB = (bf16s*)(W + 5 * EH);
  bf16s* atomh = (bf16s*)W;
  bf16s* wt_h = (bf16s*)d_out;   // stashed in d_out; k_pool overwrites later
  bf16s* wt_o = wt_h + H * H;

  k_wt<<<2, 256, 0, stream>>>(Wh, Wo, wt_h, wt_o);
  k_binput_gemm<<<EDGES / 64, 256, 0, stream>>>(fbonds, Wi, wt_h, binput8, B1);            // M1
  k_fused<0, 0><<<EDGES / 32, 128, 0, stream>>>(bgraph, B1, nullptr, binput8, wt_h, BB, nullptr); // M2 bf16
  k_fused<0, 1><<<EDGES / 32, 128, 0, stream>>>(bgraph, BB, nullptr, binput8, wt_h, QA, SA);      // M3 q8
  k_fused<1, 1><<<EDGES / 32, 128, 0, stream>>>(bgraph, QA, SA, binput8, wt_h, QB, SB);           // M4 q8
  k_fused<1, 1><<<EDGES / 32, 128, 0, stream>>>(bgraph, QB, SB, binput8, wt_h, QA, SA);           // M5 q8
  k_fused<1, 1><<<EDGES / 32, 128, 0, stream>>>(bgraph, QA, SA, binput8, wt_o, QB, SB);           // M6 q8
  k_atoms<<<NATOMS / 16, 256, 0, stream>>>(fatoms, agraph, QB, SB, Wo, bo, atomh);
  k_pool<<<NMOLS, H, 0, stream>>>(atomh, sstart, slen, out);
}

// Round 8
// 731.003 us; speedup vs baseline: 1.2334x; 1.0962x over previous
//
#include <hip/hip_runtime.h>

#define EDGES 200000
#define NATOMS 100000
#define NMOLS 2000
#define H 128
#define MAXNB 15
#define AFD 18
#define INFD 23
#define LROW 136  // LDS A-tile row stride (bf16): +8 pad, 16B-aligned rows, 2-way banks

// Precision ledger (measured):
//  R2: e4m3 tables            -> err 448 (== e4m3 sat; messages exceed +-448)
//  R3: e5m2 tables M1-M5      -> err 1088
//  R4: e5m2 M3-M5 + e4m3 binput -> err 1120 (placement irrelevant; format is the issue;
//      table COUNT barely matters: 3 vs 5 tables gave same error)
//  R5-R7: int8 per-32ch block scales (M3..M6) + e4m3 binput -> PASS
//  R8: all 6 tables q8 (count-insensitivity per R3/R4).
// Mechanics ledger (measured):
//  R6: aligned [E][128] payload + separate [E][4] scales -> q8 gather ~100us.
//  R7: VGPR=52 of 128 budget => compiler serialized the 4 row-iters (46 VMEM
//      instr each). R8: 8 lanes/row x uint4 payload, 2 iters, vectorized idx
//      loads -> ~70 VMEM instr/wave (was 184), 2 serial idx->gather chains.

typedef unsigned short bf16s;
typedef unsigned char u8;
typedef __attribute__((ext_vector_type(8))) short short8;
typedef __attribute__((ext_vector_type(4))) float f32x4;
typedef __attribute__((ext_vector_type(2))) float f32x2;
typedef unsigned int uint4u __attribute__((ext_vector_type(4), aligned(4)));

__device__ inline float bf2f(bf16s u) {
  union { unsigned int i; float f; } c; c.i = ((unsigned int)u) << 16; return c.f;
}
__device__ inline bf16s f2bf(float f) {
  union { float f; unsigned int i; } c; c.f = f;
  unsigned int lsb = (c.i >> 16) & 1u;
  c.i += 0x7fffu + lsb;              // round-to-nearest-even
  return (bf16s)(c.i >> 16);
}
__device__ inline unsigned int pack2(f32x2 v) {
  return (unsigned int)f2bf(fmaxf(v.x, 0.f)) |
         ((unsigned int)f2bf(fmaxf(v.y, 0.f)) << 16);
}
// pack 4 f32 into 4 e4m3 bytes (one dword)
__device__ inline unsigned int pack4_fp8(float a, float b, float c, float d) {
  int lo = __builtin_amdgcn_cvt_pk_fp8_f32(a, b, 0, false);
  int full = __builtin_amdgcn_cvt_pk_fp8_f32(c, d, lo, true);
  return (unsigned int)full;
}
// 16-lane max reduce on the VALU pipe via DPP row rotations (ror 1,2,4,8).
#define DPPMAX_STEP(m, CTRL)                                                   \
  {                                                                            \
    int _t = __builtin_amdgcn_update_dpp(                                      \
        0, __builtin_bit_cast(int, m), CTRL, 0xf, 0xf, false);                 \
    m = fmaxf(m, __builtin_bit_cast(float, _t));                               \
  }
__device__ inline float dpp_max16(float m) {
  DPPMAX_STEP(m, 0x121);  // row_ror:1
  DPPMAX_STEP(m, 0x122);  // row_ror:2
  DPPMAX_STEP(m, 0x124);  // row_ror:4
  DPPMAX_STEP(m, 0x128);  // row_ror:8
  return m;
}

// ------- one-time: Wt[n][k] = bf16(W[k][n]) for W_h and W_o[AFD:,:] -------
__global__ __launch_bounds__(256) void k_wt(
    const float* __restrict__ Wh, const float* __restrict__ Wo,
    bf16s* __restrict__ wt_h, bf16s* __restrict__ wt_o) {
  const float* S = blockIdx.x ? (Wo + AFD * H) : Wh;
  bf16s* D = blockIdx.x ? wt_o : wt_h;
  for (int i = threadIdx.x; i < H * H; i += 256) {
    int k = i >> 7, n = i & 127;
    D[n * H + k] = f2bf(S[i]);
  }
}

// MFMA epilogue: 16x128 @ 128x128 from wave-private LDS tile; q8 output:
// int8 payload rows [E][128] (aligned) + per-32ch bf16 scales in [E][4] Sout.
__device__ inline void mfma_epi_q8(const bf16s* Aw, const bf16s* __restrict__ Wt,
                                   u8* __restrict__ P8, bf16s* __restrict__ Sout,
                                   int ebase, int lane) {
  const int mm = lane & 15;
  const int quad = lane >> 4;
  const bf16s* Wp = Wt + (size_t)mm * H + quad * 8;
  const int rbase = ebase + quad * 4;
  f32x4 acc[2][4];
#pragma unroll
  for (int h = 0; h < 2; ++h)
#pragma unroll
    for (int i = 0; i < 4; ++i) acc[h][i] = (f32x4){0.f, 0.f, 0.f, 0.f};
#pragma unroll
  for (int kk = 0; kk < 4; ++kk) {
    short8 af = *(const short8*)&Aw[mm * LROW + quad * 8 + kk * 32];
#pragma unroll
    for (int h = 0; h < 2; ++h)
#pragma unroll
      for (int nt = 0; nt < 4; ++nt) {
        short8 bfr = *(const short8*)(Wp + (size_t)((h * 4 + nt) * 16) * H + kk * 32);
        acc[h][nt] = __builtin_amdgcn_mfma_f32_16x16x32_bf16(af, bfr, acc[h][nt], 0, 0, 0);
      }
  }
  // lane's channel c = (h*4+nt)*16+mm -> 32-ch block b = h*2 + (nt>>1)
  float m[4][4];  // [row i][block b] absmax
#pragma unroll
  for (int i = 0; i < 4; ++i)
#pragma unroll
    for (int b = 0; b < 4; ++b) m[i][b] = 0.f;
#pragma unroll
  for (int h = 0; h < 2; ++h)
#pragma unroll
    for (int nt = 0; nt < 4; ++nt) {
      const int b = h * 2 + (nt >> 1);
#pragma unroll
      for (int i = 0; i < 4; ++i) m[i][b] = fmaxf(m[i][b], fabsf(acc[h][nt][i]));
    }
#pragma unroll
  for (int i = 0; i < 4; ++i)
#pragma unroll
    for (int b = 0; b < 4; ++b) m[i][b] = dpp_max16(m[i][b]);
  float rs[4][4];
  unsigned short sbits[4][4];
#pragma unroll
  for (int i = 0; i < 4; ++i)
#pragma unroll
    for (int b = 0; b < 4; ++b) {
      bf16s sb = f2bf(m[i][b] * (1.f / 127.f));
      float sd = bf2f(sb);  // decode-exact scale
      rs[i][b] = sd > 0.f ? 1.f / sd : 0.f;
      sbits[i][b] = sb;
    }
  if (mm == 0) {
#pragma unroll
    for (int i = 0; i < 4; ++i) {
      ushort4 sv;
      sv.x = sbits[i][0]; sv.y = sbits[i][1];
      sv.z = sbits[i][2]; sv.w = sbits[i][3];
      *(ushort4*)&Sout[(size_t)(rbase + i) * 4] = sv;
    }
  }
#pragma unroll
  for (int h = 0; h < 2; ++h)
#pragma unroll
    for (int nt = 0; nt < 4; ++nt) {
      const int b = h * 2 + (nt >> 1);
#pragma unroll
      for (int i = 0; i < 4; ++i) {
        float q = fminf(fmaxf(acc[h][nt][i] * rs[i][b] + 128.5f, 0.f), 255.f);
        P8[(size_t)(rbase + i) * H + (h * 4 + nt) * 16 + mm] = (u8)(unsigned)q;
      }
    }
}

// ---- binput = fbonds @ W_i (stored e4m3); M1 = relu(binput) @ W_h (q8) ----
__global__ __launch_bounds__(256) void k_binput_gemm(
    const float* __restrict__ fbonds, const float* __restrict__ Wi,
    const bf16s* __restrict__ wt_h, u8* __restrict__ binput8,
    u8* __restrict__ P1, bf16s* __restrict__ S1) {
  __shared__ float Wl[INFD * H];
  __shared__ bf16s Am[4][16 * LROW];
  const int tid = threadIdx.x;
  for (int i = tid; i < INFD * H; i += 256) Wl[i] = Wi[i];
  __syncthreads();
  const int wave = tid >> 6;
  const int lane = tid & 63;
  bf16s* Aw = Am[wave];
  const int ebase = (blockIdx.x * 4 + wave) * 16;
  const int sub = lane >> 5;
  const int col = lane & 31;
  for (int r = 0; r < 8; ++r) {
    const int erow = r * 2 + sub;
    const int e = ebase + erow;
    const float* fb = &fbonds[(size_t)e * INFD];
    float acc[4] = {0.f, 0.f, 0.f, 0.f};
#pragma unroll
    for (int k = 0; k < INFD; ++k) {
      float f = fb[k];
      float4 w = *(const float4*)&Wl[k * H + col * 4];
      acc[0] = fmaf(f, w.x, acc[0]); acc[1] = fmaf(f, w.y, acc[1]);
      acc[2] = fmaf(f, w.z, acc[2]); acc[3] = fmaf(f, w.w, acc[3]);
    }
    *(unsigned int*)&binput8[(size_t)e * H + col * 4] =
        pack4_fp8(acc[0], acc[1], acc[2], acc[3]);
    ushort4 mq;
    mq.x = f2bf(fmaxf(acc[0], 0.f)); mq.y = f2bf(fmaxf(acc[1], 0.f));
    mq.z = f2bf(fmaxf(acc[2], 0.f)); mq.w = f2bf(fmaxf(acc[3], 0.f));
    *(ushort4*)&Aw[erow * LROW + col * 4] = mq;
  }
  asm volatile("s_waitcnt lgkmcnt(0)" ::: "memory");
  mfma_epi_q8(Aw, wt_h, P1, S1, ebase, lane);
}

// ---- fused depth step: Pout = (relu(binput + sum_j P[bgraph[e][j]])) @ Wt ----
// All tables q8. 8 lanes x 16B (uint4) cover one 128B row; 8 rows per load
// instruction; 2 outer iterations per wave (16 rows).
// decode: acc_c = binput_c + sum_j s_j*u_jc - 128*sum_j s_j.
__global__ __launch_bounds__(128, 4) void k_fusedq(
    const int* __restrict__ bgraph, const u8* __restrict__ P,
    const bf16s* __restrict__ Sin, const u8* __restrict__ binput8,
    const bf16s* __restrict__ Wt, u8* __restrict__ Pout,
    bf16s* __restrict__ Sout) {
  __shared__ bf16s Am[2][16 * LROW];
  const int tid = threadIdx.x;
  const int wave = tid >> 6;
  const int lane = tid & 63;
  bf16s* Aw = Am[wave];
  const int ebase = (blockIdx.x * 2 + wave) * 16;

  const int sub = lane >> 3;   // 8 rows per iteration
  const int col = lane & 7;    // 8 lanes x 16 channels = 128 cols
#pragma unroll
  for (int it = 0; it < 2; ++it) {
    const int erow = it * 8 + sub;
    const int e = ebase + erow;
    const int* bg = &bgraph[(size_t)e * MAXNB];
    uint4u i0 = *(const uint4u*)(bg + 0);
    uint4u i1 = *(const uint4u*)(bg + 4);
    uint4u i2 = *(const uint4u*)(bg + 8);
    int idx[MAXNB];
    idx[0] = i0.x; idx[1] = i0.y; idx[2] = i0.z; idx[3] = i0.w;
    idx[4] = i1.x; idx[5] = i1.y; idx[6] = i1.z; idx[7] = i1.w;
    idx[8] = i2.x; idx[9] = i2.y; idx[10] = i2.z; idx[11] = i2.w;
    idx[12] = bg[12]; idx[13] = bg[13]; idx[14] = bg[14];

    uint4 t[MAXNB];
    float s[MAXNB];
#pragma unroll
    for (int j = 0; j < MAXNB; ++j) {
      t[j] = *(const uint4*)&P[(size_t)idx[j] * H + col * 16];
      s[j] = bf2f(Sin[(size_t)idx[j] * 4 + (col >> 1)]);
    }
    uint4 bi = *(const uint4*)&binput8[(size_t)e * H + col * 16];
    f32x2 acc[8];
    acc[0] = __builtin_amdgcn_cvt_pk_f32_fp8(bi.x, false);
    acc[1] = __builtin_amdgcn_cvt_pk_f32_fp8(bi.x, true);
    acc[2] = __builtin_amdgcn_cvt_pk_f32_fp8(bi.y, false);
    acc[3] = __builtin_amdgcn_cvt_pk_f32_fp8(bi.y, true);
    acc[4] = __builtin_amdgcn_cvt_pk_f32_fp8(bi.z, false);
    acc[5] = __builtin_amdgcn_cvt_pk_f32_fp8(bi.z, true);
    acc[6] = __builtin_amdgcn_cvt_pk_f32_fp8(bi.w, false);
    acc[7] = __builtin_amdgcn_cvt_pk_f32_fp8(bi.w, true);
    float ssum = 0.f;
#pragma unroll
    for (int j = 0; j < MAXNB; ++j) ssum += s[j];
#pragma unroll
    for (int j = 0; j < MAXNB; ++j) {
      const float sj = s[j];
      const unsigned w0 = t[j].x, w1 = t[j].y, w2 = t[j].z, w3 = t[j].w;
      acc[0].x = fmaf(sj, (float)(w0 & 0xffu), acc[0].x);
      acc[0].y = fmaf(sj, (float)((w0 >> 8) & 0xffu), acc[0].y);
      acc[1].x = fmaf(sj, (float)((w0 >> 16) & 0xffu), acc[1].x);
      acc[1].y = fmaf(sj, (float)(w0 >> 24), acc[1].y);
      acc[2].x = fmaf(sj, (float)(w1 & 0xffu), acc[2].x);
      acc[2].y = fmaf(sj, (float)((w1 >> 8) & 0xffu), acc[2].y);
      acc[3].x = fmaf(sj, (float)((w1 >> 16) & 0xffu), acc[3].x);
      acc[3].y = fmaf(sj, (float)(w1 >> 24), acc[3].y);
      acc[4].x = fmaf(sj, (float)(w2 & 0xffu), acc[4].x);
      acc[4].y = fmaf(sj, (float)((w2 >> 8) & 0xffu), acc[4].y);
      acc[5].x = fmaf(sj, (float)((w2 >> 16) & 0xffu), acc[5].x);
      acc[5].y = fmaf(sj, (float)(w2 >> 24), acc[5].y);
      acc[6].x = fmaf(sj, (float)(w3 & 0xffu), acc[6].x);
      acc[6].y = fmaf(sj, (float)((w3 >> 8) & 0xffu), acc[6].y);
      acc[7].x = fmaf(sj, (float)((w3 >> 16) & 0xffu), acc[7].x);
      acc[7].y = fmaf(sj, (float)(w3 >> 24), acc[7].y);
    }
    const float off = 128.f * ssum;
#pragma unroll
    for (int k = 0; k < 8; ++k) { acc[k].x -= off; acc[k].y -= off; }
    uint4 o0, o1;
    o0.x = pack2(acc[0]); o0.y = pack2(acc[1]);
    o0.z = pack2(acc[2]); o0.w = pack2(acc[3]);
    o1.x = pack2(acc[4]); o1.y = pack2(acc[5]);
    o1.z = pack2(acc[6]); o1.w = pack2(acc[7]);
    *(uint4*)&Aw[erow * LROW + col * 16] = o0;
    *(uint4*)&Aw[erow * LROW + col * 16 + 8] = o1;
  }
  asm volatile("s_waitcnt lgkmcnt(0)" ::: "memory");
  mfma_epi_q8(Aw, Wt, Pout, Sout, ebase, lane);
}

// atom_hiddens = relu(fatoms @ Wo[0:18] + sum_j msg[agraph[a][j]] + b_o)
// q8 gather, 8 lanes x 16 channels per atom; 32 atoms per 256-thread block.
__global__ __launch_bounds__(256, 4) void k_atoms(
    const float* __restrict__ fatoms, const int* __restrict__ agraph,
    const u8* __restrict__ msgQ, const bf16s* __restrict__ msgS,
    const float* __restrict__ Wo, const float* __restrict__ bo,
    bf16s* __restrict__ atomh) {
  __shared__ float Wl[AFD * H];
  const int tid = threadIdx.x;
  for (int i = tid; i < AFD * H; i += 256) Wl[i] = Wo[i];
  __syncthreads();
  const int col = tid & 7;
  const int a = blockIdx.x * 32 + (tid >> 3);
  const int* ag = &agraph[(size_t)a * MAXNB];
  uint4u i0 = *(const uint4u*)(ag + 0);
  uint4u i1 = *(const uint4u*)(ag + 4);
  uint4u i2 = *(const uint4u*)(ag + 8);
  int idx[MAXNB];
  idx[0] = i0.x; idx[1] = i0.y; idx[2] = i0.z; idx[3] = i0.w;
  idx[4] = i1.x; idx[5] = i1.y; idx[6] = i1.z; idx[7] = i1.w;
  idx[8] = i2.x; idx[9] = i2.y; idx[10] = i2.z; idx[11] = i2.w;
  idx[12] = ag[12]; idx[13] = ag[13]; idx[14] = ag[14];
  uint4 t[MAXNB];
  float s[MAXNB];
#pragma unroll
  for (int j = 0; j < MAXNB; ++j) {
    t[j] = *(const uint4*)&msgQ[(size_t)idx[j] * H + col * 16];
    s[j] = bf2f(msgS[(size_t)idx[j] * 4 + (col >> 1)]);
  }
  f32x2 acc[8];
#pragma unroll
  for (int k = 0; k < 4; ++k) {
    float4 b = ((const float4*)bo)[col * 4 + k];
    acc[2 * k] = (f32x2){b.x, b.y};
    acc[2 * k + 1] = (f32x2){b.z, b.w};
  }
#pragma unroll
  for (int k = 0; k < AFD; ++k) {
    float f = fatoms[(size_t)a * AFD + k];
#pragma unroll
    for (int q = 0; q < 4; ++q) {
      float4 w = ((const float4*)&Wl[k * H + col * 16])[q];
      acc[2 * q].x = fmaf(f, w.x, acc[2 * q].x);
      acc[2 * q].y = fmaf(f, w.y, acc[2 * q].y);
      acc[2 * q + 1].x = fmaf(f, w.z, acc[2 * q + 1].x);
      acc[2 * q + 1].y = fmaf(f, w.w, acc[2 * q + 1].y);
    }
  }
  float ssum = 0.f;
#pragma unroll
  for (int j = 0; j < MAXNB; ++j) ssum += s[j];
#pragma unroll
  for (int j = 0; j < MAXNB; ++j) {
    const float sj = s[j];
    const unsigned w0 = t[j].x, w1 = t[j].y, w2 = t[j].z, w3 = t[j].w;
    acc[0].x = fmaf(sj, (float)(w0 & 0xffu), acc[0].x);
    acc[0].y = fmaf(sj, (float)((w0 >> 8) & 0xffu), acc[0].y);
    acc[1].x = fmaf(sj, (float)((w0 >> 16) & 0xffu), acc[1].x);
    acc[1].y = fmaf(sj, (float)(w0 >> 24), acc[1].y);
    acc[2].x = fmaf(sj, (float)(w1 & 0xffu), acc[2].x);
    acc[2].y = fmaf(sj, (float)((w1 >> 8) & 0xffu), acc[2].y);
    acc[3].x = fmaf(sj, (float)((w1 >> 16) & 0xffu), acc[3].x);
    acc[3].y = fmaf(sj, (float)(w1 >> 24), acc[3].y);
    acc[4].x = fmaf(sj, (float)(w2 & 0xffu), acc[4].x);
    acc[4].y = fmaf(sj, (float)((w2 >> 8) & 0xffu), acc[4].y);
    acc[5].x = fmaf(sj, (float)((w2 >> 16) & 0xffu), acc[5].x);
    acc[5].y = fmaf(sj, (float)(w2 >> 24), acc[5].y);
    acc[6].x = fmaf(sj, (float)(w3 & 0xffu), acc[6].x);
    acc[6].y = fmaf(sj, (float)((w3 >> 8) & 0xffu), acc[6].y);
    acc[7].x = fmaf(sj, (float)((w3 >> 16) & 0xffu), acc[7].x);
    acc[7].y = fmaf(sj, (float)(w3 >> 24), acc[7].y);
  }
  const float off = 128.f * ssum;
#pragma unroll
  for (int k = 0; k < 8; ++k) { acc[k].x -= off; acc[k].y -= off; }
  uint4 o0, o1;
  o0.x = pack2(acc[0]); o0.y = pack2(acc[1]);
  o0.z = pack2(acc[2]); o0.w = pack2(acc[3]);
  o1.x = pack2(acc[4]); o1.y = pack2(acc[5]);
  o1.z = pack2(acc[6]); o1.w = pack2(acc[7]);
  *(uint4*)&atomh[(size_t)a * H + col * 16] = o0;
  *(uint4*)&atomh[(size_t)a * H + col * 16 + 8] = o1;
}

// ---------------- segment mean pool (bf16 in, f32 out) ----------------
__global__ void k_pool(const bf16s* __restrict__ atomh,
                       const int* __restrict__ sstart, const int* __restrict__ slen,
                       float* __restrict__ out) {
  const int m = blockIdx.x;
  const int c = threadIdx.x;
  const int s = sstart[m];
  const int L = slen[m];
  float sum = 0.f;
  for (int i = 0; i < L; ++i) sum += bf2f(atomh[(size_t)(s + i) * H + c]);
  out[m * H + c] = sum / (float)L;
}

extern "C" void kernel_launch(void* const* d_in, const int* in_sizes, int n_in,
                              void* d_out, int out_size, void* d_ws, size_t ws_size,
                              hipStream_t stream) {
  const float* fatoms = (const float*)d_in[0];
  const float* fbonds = (const float*)d_in[1];
  const int* agraph = (const int*)d_in[2];
  const int* bgraph = (const int*)d_in[3];
  const int* sstart = (const int*)d_in[4];
  const int* slen = (const int*)d_in[5];
  const float* Wi = (const float*)d_in[6];
  const float* Wh = (const float*)d_in[7];
  const float* Wo = (const float*)d_in[8];
  const float* bo = (const float*)d_in[9];
  float* out = (float*)d_out;

  const size_t EH = (size_t)EDGES * H;   // 25.6M bytes for q8 tables
  // Workspace (~81 MB of the budget):
  //  [0,    EH) binput8 e4m3 (dead after M6; atomh bf16 = NATOMS*H*2 = EH overlays)
  //  [EH,  2EH) QA payload | [2EH, 3EH) QB payload
  //  [3EH, ...) SA scales (1.6MB) | SB scales (1.6MB)
  char* W = (char*)d_ws;
  u8*    binput8 = (u8*)W;
  u8*    QA = (u8*)(W + EH);
  u8*    QB = (u8*)(W + 2 * EH);
  bf16s* SA = (bf16s*)(W + 3 * EH);
  bf16s* SB = (bf16s*)(W + 3 * EH + (size_t)EDGES * 8);
  bf16s* atomh = (bf16s*)W;
  bf16s* wt_h = (bf16s*)d_out;   // stashed in d_out; k_pool overwrites later
  bf16s* wt_o = wt_h + H * H;

  k_wt<<<2, 256, 0, stream>>>(Wh, Wo, wt_h, wt_o);
  k_binput_gemm<<<EDGES / 64, 256, 0, stream>>>(fbonds, Wi, wt_h, binput8, QA, SA);   // M1
  k_fusedq<<<EDGES / 32, 128, 0, stream>>>(bgraph, QA, SA, binput8, wt_h, QB, SB);    // M2
  k_fusedq<<<EDGES / 32, 128, 0, stream>>>(bgraph, QB, SB, binput8, wt_h, QA, SA);    // M3
  k_fusedq<<<EDGES / 32, 128, 0, stream>>>(bgraph, QA, SA, binput8, wt_h, QB, SB);    // M4
  k_fusedq<<<EDGES / 32, 128, 0, stream>>>(bgraph, QB, SB, binput8, wt_h, QA, SA);    // M5
  k_fusedq<<<EDGES / 32, 128, 0, stream>>>(bgraph, QA, SA, binput8, wt_o, QB, SB);    // M6
  k_atoms<<<NATOMS / 32, 256, 0, stream>>>(fatoms, agraph, QB, SB, Wo, bo, atomh);
  k_pool<<<NMOLS, H, 0, stream>>>(atomh, sstart, slen, out);
}

// Round 9
// 697.286 us; speedup vs baseline: 1.2931x; 1.0484x over previous
//
#include <hip/hip_runtime.h>

#define EDGES 200000
#define NATOMS 100000
#define NMOLS 2000
#define H 128
#define MAXNB 15
#define AFD 18
#define INFD 23
#define LROW 136  // LDS A-tile row stride (bf16): +8 pad, 16B-aligned rows, 2-way banks
#define K1 32     // GEMM1 K (INFD=23 zero-padded to 32)
#define AROW 40   // GEMM1 LDS A-tile row stride (bf16 shorts)

// Precision ledger (measured):
//  R2: e4m3 tables -> err 448 (sat). R3/R4: e5m2 -> 1088/1120 (format-bound).
//  R5-R7: int8 per-32ch block-scale tables + e4m3 binput -> PASS (err 136).
//  R8: all 6 tables q8 -> PASS err 136.
//  R9: GEMM1 (fbonds@Wi) via bf16 MFMA: +0.3-0.5% rel on binput, under the
//      e4m3 storage error it already survives.
// Mechanics ledger (measured):
//  R8: 8 lanes/row uint4 gather -> all fusedq ~<100us. NEW top cost:
//      k_binput_gemm 110us @ 7% HBM, 32% VALU, 2% MFMA = scalar-GEMM bound
//      (184 LDS float4 + 736 scalar FMA per thread). R9: 8 MFMA/wave instead.

typedef unsigned short bf16s;
typedef unsigned char u8;
typedef __attribute__((ext_vector_type(8))) short short8;
typedef __attribute__((ext_vector_type(4))) float f32x4;
typedef __attribute__((ext_vector_type(2))) float f32x2;
typedef unsigned int uint4u __attribute__((ext_vector_type(4), aligned(4)));

__device__ inline float bf2f(bf16s u) {
  union { unsigned int i; float f; } c; c.i = ((unsigned int)u) << 16; return c.f;
}
__device__ inline bf16s f2bf(float f) {
  union { float f; unsigned int i; } c; c.f = f;
  unsigned int lsb = (c.i >> 16) & 1u;
  c.i += 0x7fffu + lsb;              // round-to-nearest-even
  return (bf16s)(c.i >> 16);
}
__device__ inline unsigned int pack2(f32x2 v) {
  return (unsigned int)f2bf(fmaxf(v.x, 0.f)) |
         ((unsigned int)f2bf(fmaxf(v.y, 0.f)) << 16);
}
// 16-lane max reduce on the VALU pipe via DPP row rotations (ror 1,2,4,8).
#define DPPMAX_STEP(m, CTRL)                                                   \
  {                                                                            \
    int _t = __builtin_amdgcn_update_dpp(                                      \
        0, __builtin_bit_cast(int, m), CTRL, 0xf, 0xf, false);                 \
    m = fmaxf(m, __builtin_bit_cast(float, _t));                               \
  }
__device__ inline float dpp_max16(float m) {
  DPPMAX_STEP(m, 0x121);  // row_ror:1
  DPPMAX_STEP(m, 0x122);  // row_ror:2
  DPPMAX_STEP(m, 0x124);  // row_ror:4
  DPPMAX_STEP(m, 0x128);  // row_ror:8
  return m;
}

// ------- one-time transposed bf16 weights -------
// blk 0: wt_h[n][128] = Wh[k][n];  blk 1: wt_o[n][128] = Wo[AFD+k][n];
// blk 2: wt_i[n][32]  = Wi[k][n] (k<23; zero-pad 23..31)
__global__ __launch_bounds__(256) void k_wt(
    const float* __restrict__ Wh, const float* __restrict__ Wo,
    const float* __restrict__ Wi, bf16s* __restrict__ wt_h,
    bf16s* __restrict__ wt_o, bf16s* __restrict__ wt_i) {
  if (blockIdx.x == 2) {
    for (int i = threadIdx.x; i < H * K1; i += 256) {
      int n = i >> 5, k = i & 31;
      wt_i[i] = (k < INFD) ? f2bf(Wi[k * H + n]) : (bf16s)0;
    }
    return;
  }
  const float* S = blockIdx.x ? (Wo + AFD * H) : Wh;
  bf16s* D = blockIdx.x ? wt_o : wt_h;
  for (int i = threadIdx.x; i < H * H; i += 256) {
    int k = i >> 7, n = i & 127;
    D[n * H + k] = f2bf(S[i]);
  }
}

// MFMA epilogue: 16x128 @ 128x128 from wave-private LDS tile; q8 output:
// int8 payload rows [E][128] (aligned) + per-32ch bf16 scales in [E][4] Sout.
__device__ inline void mfma_epi_q8(const bf16s* Aw, const bf16s* __restrict__ Wt,
                                   u8* __restrict__ P8, bf16s* __restrict__ Sout,
                                   int ebase, int lane) {
  const int mm = lane & 15;
  const int quad = lane >> 4;
  const bf16s* Wp = Wt + (size_t)mm * H + quad * 8;
  const int rbase = ebase + quad * 4;
  f32x4 acc[2][4];
#pragma unroll
  for (int h = 0; h < 2; ++h)
#pragma unroll
    for (int i = 0; i < 4; ++i) acc[h][i] = (f32x4){0.f, 0.f, 0.f, 0.f};
#pragma unroll
  for (int kk = 0; kk < 4; ++kk) {
    short8 af = *(const short8*)&Aw[mm * LROW + quad * 8 + kk * 32];
#pragma unroll
    for (int h = 0; h < 2; ++h)
#pragma unroll
      for (int nt = 0; nt < 4; ++nt) {
        short8 bfr = *(const short8*)(Wp + (size_t)((h * 4 + nt) * 16) * H + kk * 32);
        acc[h][nt] = __builtin_amdgcn_mfma_f32_16x16x32_bf16(af, bfr, acc[h][nt], 0, 0, 0);
      }
  }
  // lane's channel c = (h*4+nt)*16+mm -> 32-ch block b = h*2 + (nt>>1)
  float m[4][4];  // [row i][block b] absmax
#pragma unroll
  for (int i = 0; i < 4; ++i)
#pragma unroll
    for (int b = 0; b < 4; ++b) m[i][b] = 0.f;
#pragma unroll
  for (int h = 0; h < 2; ++h)
#pragma unroll
    for (int nt = 0; nt < 4; ++nt) {
      const int b = h * 2 + (nt >> 1);
#pragma unroll
      for (int i = 0; i < 4; ++i) m[i][b] = fmaxf(m[i][b], fabsf(acc[h][nt][i]));
    }
#pragma unroll
  for (int i = 0; i < 4; ++i)
#pragma unroll
    for (int b = 0; b < 4; ++b) m[i][b] = dpp_max16(m[i][b]);
  float rs[4][4];
  unsigned short sbits[4][4];
#pragma unroll
  for (int i = 0; i < 4; ++i)
#pragma unroll
    for (int b = 0; b < 4; ++b) {
      bf16s sb = f2bf(m[i][b] * (1.f / 127.f));
      float sd = bf2f(sb);  // decode-exact scale
      rs[i][b] = sd > 0.f ? 1.f / sd : 0.f;
      sbits[i][b] = sb;
    }
  if (mm == 0) {
#pragma unroll
    for (int i = 0; i < 4; ++i) {
      ushort4 sv;
      sv.x = sbits[i][0]; sv.y = sbits[i][1];
      sv.z = sbits[i][2]; sv.w = sbits[i][3];
      *(ushort4*)&Sout[(size_t)(rbase + i) * 4] = sv;
    }
  }
#pragma unroll
  for (int h = 0; h < 2; ++h)
#pragma unroll
    for (int nt = 0; nt < 4; ++nt) {
      const int b = h * 2 + (nt >> 1);
#pragma unroll
      for (int i = 0; i < 4; ++i) {
        float q = fminf(fmaxf(acc[h][nt][i] * rs[i][b] + 128.5f, 0.f), 255.f);
        P8[(size_t)(rbase + i) * H + (h * 4 + nt) * 16 + mm] = (u8)(unsigned)q;
      }
    }
}

// ---- binput = fbonds @ W_i via MFMA (e4m3 out); M1 = relu(binput)@W_h (q8) ----
// GEMM1: A = bf16(fbonds) 16x32 (K=23 zero-padded), B = wt_i[n][32].
// GEMM1's C-layout (col=lane&15,row=quad*4+i) feeds binput8 stores and the
// relu'd bf16 A-tile for the existing GEMM2 epilogue directly.
__global__ __launch_bounds__(256) void k_binput_gemm(
    const float* __restrict__ fbonds, const bf16s* __restrict__ wt_i,
    const bf16s* __restrict__ wt_h, u8* __restrict__ binput8,
    u8* __restrict__ P1, bf16s* __restrict__ S1) {
  __shared__ bf16s At[4][16 * AROW];
  __shared__ bf16s Am[4][16 * LROW];
  const int tid = threadIdx.x;
  const int wave = tid >> 6;
  const int lane = tid & 63;
  bf16s* A1 = At[wave];
  bf16s* Aw = Am[wave];
  const int ebase = (blockIdx.x * 4 + wave) * 16;

  // zero the A1 tile (covers the K=23..31 pad), then stage fbonds as bf16
  for (int i = lane; i < 16 * AROW / 2; i += 64) ((unsigned int*)A1)[i] = 0u;
  const float* fb = &fbonds[(size_t)ebase * INFD];
#pragma unroll
  for (int it = 0; it < 6; ++it) {
    int idx = it * 64 + lane;
    if (idx < 16 * INFD) {
      int er = idx / INFD;
      int k = idx - er * INFD;
      A1[er * AROW + k] = f2bf(fb[idx]);
    }
  }
  asm volatile("s_waitcnt lgkmcnt(0)" ::: "memory");

  const int mm = lane & 15;
  const int quad = lane >> 4;
  const int rbase = ebase + quad * 4;
  short8 af = *(const short8*)&A1[mm * AROW + quad * 8];
  const bf16s* Wp = wt_i + mm * K1 + quad * 8;
  f32x4 acc1[8];
#pragma unroll
  for (int nt = 0; nt < 8; ++nt) {
    short8 bfr = *(const short8*)(Wp + (size_t)(nt * 16) * K1);
    acc1[nt] = __builtin_amdgcn_mfma_f32_16x16x32_bf16(
        af, bfr, (f32x4){0.f, 0.f, 0.f, 0.f}, 0, 0, 0);
  }
  // binput8 e4m3 stores + relu->bf16 into GEMM2 A-tile
#pragma unroll
  for (int nt = 0; nt < 8; ++nt) {
#pragma unroll
    for (int i = 0; i < 4; ++i) {
      int d = __builtin_amdgcn_cvt_pk_fp8_f32(acc1[nt][i], acc1[nt][i], 0, false);
      binput8[(size_t)(rbase + i) * H + nt * 16 + mm] = (u8)(d & 0xff);
      Aw[(quad * 4 + i) * LROW + nt * 16 + mm] = f2bf(fmaxf(acc1[nt][i], 0.f));
    }
  }
  asm volatile("s_waitcnt lgkmcnt(0)" ::: "memory");
  mfma_epi_q8(Aw, wt_h, P1, S1, ebase, lane);
}

// ---- fused depth step: Pout = (relu(binput + sum_j P[bgraph[e][j]])) @ Wt ----
// All tables q8. 8 lanes x 16B (uint4) cover one 128B row; 8 rows per load
// instruction; 2 outer iterations per wave (16 rows).
// decode: acc_c = binput_c + sum_j s_j*u_jc - 128*sum_j s_j.
__global__ __launch_bounds__(128, 4) void k_fusedq(
    const int* __restrict__ bgraph, const u8* __restrict__ P,
    const bf16s* __restrict__ Sin, const u8* __restrict__ binput8,
    const bf16s* __restrict__ Wt, u8* __restrict__ Pout,
    bf16s* __restrict__ Sout) {
  __shared__ bf16s Am[2][16 * LROW];
  const int tid = threadIdx.x;
  const int wave = tid >> 6;
  const int lane = tid & 63;
  bf16s* Aw = Am[wave];
  const int ebase = (blockIdx.x * 2 + wave) * 16;

  const int sub = lane >> 3;   // 8 rows per iteration
  const int col = lane & 7;    // 8 lanes x 16 channels = 128 cols
#pragma unroll
  for (int it = 0; it < 2; ++it) {
    const int erow = it * 8 + sub;
    const int e = ebase + erow;
    const int* bg = &bgraph[(size_t)e * MAXNB];
    uint4u i0 = *(const uint4u*)(bg + 0);
    uint4u i1 = *(const uint4u*)(bg + 4);
    uint4u i2 = *(const uint4u*)(bg + 8);
    int idx[MAXNB];
    idx[0] = i0.x; idx[1] = i0.y; idx[2] = i0.z; idx[3] = i0.w;
    idx[4] = i1.x; idx[5] = i1.y; idx[6] = i1.z; idx[7] = i1.w;
    idx[8] = i2.x; idx[9] = i2.y; idx[10] = i2.z; idx[11] = i2.w;
    idx[12] = bg[12]; idx[13] = bg[13]; idx[14] = bg[14];

    uint4 t[MAXNB];
    float s[MAXNB];
#pragma unroll
    for (int j = 0; j < MAXNB; ++j) {
      t[j] = *(const uint4*)&P[(size_t)idx[j] * H + col * 16];
      s[j] = bf2f(Sin[(size_t)idx[j] * 4 + (col >> 1)]);
    }
    uint4 bi = *(const uint4*)&binput8[(size_t)e * H + col * 16];
    f32x2 acc[8];
    acc[0] = __builtin_amdgcn_cvt_pk_f32_fp8(bi.x, false);
    acc[1] = __builtin_amdgcn_cvt_pk_f32_fp8(bi.x, true);
    acc[2] = __builtin_amdgcn_cvt_pk_f32_fp8(bi.y, false);
    acc[3] = __builtin_amdgcn_cvt_pk_f32_fp8(bi.y, true);
    acc[4] = __builtin_amdgcn_cvt_pk_f32_fp8(bi.z, false);
    acc[5] = __builtin_amdgcn_cvt_pk_f32_fp8(bi.z, true);
    acc[6] = __builtin_amdgcn_cvt_pk_f32_fp8(bi.w, false);
    acc[7] = __builtin_amdgcn_cvt_pk_f32_fp8(bi.w, true);
    float ssum = 0.f;
#pragma unroll
    for (int j = 0; j < MAXNB; ++j) ssum += s[j];
#pragma unroll
    for (int j = 0; j < MAXNB; ++j) {
      const float sj = s[j];
      const unsigned w0 = t[j].x, w1 = t[j].y, w2 = t[j].z, w3 = t[j].w;
      acc[0].x = fmaf(sj, (float)(w0 & 0xffu), acc[0].x);
      acc[0].y = fmaf(sj, (float)((w0 >> 8) & 0xffu), acc[0].y);
      acc[1].x = fmaf(sj, (float)((w0 >> 16) & 0xffu), acc[1].x);
      acc[1].y = fmaf(sj, (float)(w0 >> 24), acc[1].y);
      acc[2].x = fmaf(sj, (float)(w1 & 0xffu), acc[2].x);
      acc[2].y = fmaf(sj, (float)((w1 >> 8) & 0xffu), acc[2].y);
      acc[3].x = fmaf(sj, (float)((w1 >> 16) & 0xffu), acc[3].x);
      acc[3].y = fmaf(sj, (float)(w1 >> 24), acc[3].y);
      acc[4].x = fmaf(sj, (float)(w2 & 0xffu), acc[4].x);
      acc[4].y = fmaf(sj, (float)((w2 >> 8) & 0xffu), acc[4].y);
      acc[5].x = fmaf(sj, (float)((w2 >> 16) & 0xffu), acc[5].x);
      acc[5].y = fmaf(sj, (float)(w2 >> 24), acc[5].y);
      acc[6].x = fmaf(sj, (float)(w3 & 0xffu), acc[6].x);
      acc[6].y = fmaf(sj, (float)((w3 >> 8) & 0xffu), acc[6].y);
      acc[7].x = fmaf(sj, (float)((w3 >> 16) & 0xffu), acc[7].x);
      acc[7].y = fmaf(sj, (float)(w3 >> 24), acc[7].y);
    }
    const float off = 128.f * ssum;
#pragma unroll
    for (int k = 0; k < 8; ++k) { acc[k].x -= off; acc[k].y -= off; }
    uint4 o0, o1;
    o0.x = pack2(acc[0]); o0.y = pack2(acc[1]);
    o0.z = pack2(acc[2]); o0.w = pack2(acc[3]);
    o1.x = pack2(acc[4]); o1.y = pack2(acc[5]);
    o1.z = pack2(acc[6]); o1.w = pack2(acc[7]);
    *(uint4*)&Aw[erow * LROW + col * 16] = o0;
    *(uint4*)&Aw[erow * LROW + col * 16 + 8] = o1;
  }
  asm volatile("s_waitcnt lgkmcnt(0)" ::: "memory");
  mfma_epi_q8(Aw, Wt, Pout, Sout, ebase, lane);
}

// atom_hiddens = relu(fatoms @ Wo[0:18] + sum_j msg[agraph[a][j]] + b_o)
// q8 gather, 8 lanes x 16 channels per atom; 32 atoms per 256-thread block.
__global__ __launch_bounds__(256, 4) void k_atoms(
    const float* __restrict__ fatoms, const int* __restrict__ agraph,
    const u8* __restrict__ msgQ, const bf16s* __restrict__ msgS,
    const float* __restrict__ Wo, const float* __restrict__ bo,
    bf16s* __restrict__ atomh) {
  __shared__ float Wl[AFD * H];
  const int tid = threadIdx.x;
  for (int i = tid; i < AFD * H; i += 256) Wl[i] = Wo[i];
  __syncthreads();
  const int col = tid & 7;
  const int a = blockIdx.x * 32 + (tid >> 3);
  const int* ag = &agraph[(size_t)a * MAXNB];
  uint4u i0 = *(const uint4u*)(ag + 0);
  uint4u i1 = *(const uint4u*)(ag + 4);
  uint4u i2 = *(const uint4u*)(ag + 8);
  int idx[MAXNB];
  idx[0] = i0.x; idx[1] = i0.y; idx[2] = i0.z; idx[3] = i0.w;
  idx[4] = i1.x; idx[5] = i1.y; idx[6] = i1.z; idx[7] = i1.w;
  idx[8] = i2.x; idx[9] = i2.y; idx[10] = i2.z; idx[11] = i2.w;
  idx[12] = ag[12]; idx[13] = ag[13]; idx[14] = ag[14];
  uint4 t[MAXNB];
  float s[MAXNB];
#pragma unroll
  for (int j = 0; j < MAXNB; ++j) {
    t[j] = *(const uint4*)&msgQ[(size_t)idx[j] * H + col * 16];
    s[j] = bf2f(msgS[(size_t)idx[j] * 4 + (col >> 1)]);
  }
  f32x2 acc[8];
#pragma unroll
  for (int k = 0; k < 4; ++k) {
    float4 b = ((const float4*)bo)[col * 4 + k];
    acc[2 * k] = (f32x2){b.x, b.y};
    acc[2 * k + 1] = (f32x2){b.z, b.w};
  }
#pragma unroll
  for (int k = 0; k < AFD; ++k) {
    float f = fatoms[(size_t)a * AFD + k];
#pragma unroll
    for (int q = 0; q < 4; ++q) {
      float4 w = ((const float4*)&Wl[k * H + col * 16])[q];
      acc[2 * q].x = fmaf(f, w.x, acc[2 * q].x);
      acc[2 * q].y = fmaf(f, w.y, acc[2 * q].y);
      acc[2 * q + 1].x = fmaf(f, w.z, acc[2 * q + 1].x);
      acc[2 * q + 1].y = fmaf(f, w.w, acc[2 * q + 1].y);
    }
  }
  float ssum = 0.f;
#pragma unroll
  for (int j = 0; j < MAXNB; ++j) ssum += s[j];
#pragma unroll
  for (int j = 0; j < MAXNB; ++j) {
    const float sj = s[j];
    const unsigned w0 = t[j].x, w1 = t[j].y, w2 = t[j].z, w3 = t[j].w;
    acc[0].x = fmaf(sj, (float)(w0 & 0xffu), acc[0].x);
    acc[0].y = fmaf(sj, (float)((w0 >> 8) & 0xffu), acc[0].y);
    acc[1].x = fmaf(sj, (float)((w0 >> 16) & 0xffu), acc[1].x);
    acc[1].y = fmaf(sj, (float)(w0 >> 24), acc[1].y);
    acc[2].x = fmaf(sj, (float)(w1 & 0xffu), acc[2].x);
    acc[2].y = fmaf(sj, (float)((w1 >> 8) & 0xffu), acc[2].y);
    acc[3].x = fmaf(sj, (float)((w1 >> 16) & 0xffu), acc[3].x);
    acc[3].y = fmaf(sj, (float)(w1 >> 24), acc[3].y);
    acc[4].x = fmaf(sj, (float)(w2 & 0xffu), acc[4].x);
    acc[4].y = fmaf(sj, (float)((w2 >> 8) & 0xffu), acc[4].y);
    acc[5].x = fmaf(sj, (float)((w2 >> 16) & 0xffu), acc[5].x);
    acc[5].y = fmaf(sj, (float)(w2 >> 24), acc[5].y);
    acc[6].x = fmaf(sj, (float)(w3 & 0xffu), acc[6].x);
    acc[6].y = fmaf(sj, (float)((w3 >> 8) & 0xffu), acc[6].y);
    acc[7].x = fmaf(sj, (float)((w3 >> 16) & 0xffu), acc[7].x);
    acc[7].y = fmaf(sj, (float)(w3 >> 24), acc[7].y);
  }
  const float off = 128.f * ssum;
#pragma unroll
  for (int k = 0; k < 8; ++k) { acc[k].x -= off; acc[k].y -= off; }
  uint4 o0, o1;
  o0.x = pack2(acc[0]); o0.y = pack2(acc[1]);
  o0.z = pack2(acc[2]); o0.w = pack2(acc[3]);
  o1.x = pack2(acc[4]); o1.y = pack2(acc[5]);
  o1.z = pack2(acc[6]); o1.w = pack2(acc[7]);
  *(uint4*)&atomh[(size_t)a * H + col * 16] = o0;
  *(uint4*)&atomh[(size_t)a * H + col * 16 + 8] = o1;
}

// ---------------- segment mean pool (bf16 in, f32 out) ----------------
__global__ void k_pool(const bf16s* __restrict__ atomh,
                       const int* __restrict__ sstart, const int* __restrict__ slen,
                       float* __restrict__ out) {
  const int m = blockIdx.x;
  const int c = threadIdx.x;
  const int s = sstart[m];
  const int L = slen[m];
  float sum = 0.f;
  for (int i = 0; i < L; ++i) sum += bf2f(atomh[(size_t)(s + i) * H + c]);
  out[m * H + c] = sum / (float)L;
}

extern "C" void kernel_launch(void* const* d_in, const int* in_sizes, int n_in,
                              void* d_out, int out_size, void* d_ws, size_t ws_size,
                              hipStream_t stream) {
  const float* fatoms = (const float*)d_in[0];
  const float* fbonds = (const float*)d_in[1];
  const int* agraph = (const int*)d_in[2];
  const int* bgraph = (const int*)d_in[3];
  const int* sstart = (const int*)d_in[4];
  const int* slen = (const int*)d_in[5];
  const float* Wi = (const float*)d_in[6];
  const float* Wh = (const float*)d_in[7];
  const float* Wo = (const float*)d_in[8];
  const float* bo = (const float*)d_in[9];
  float* out = (float*)d_out;

  const size_t EH = (size_t)EDGES * H;   // 25.6M bytes for q8 tables
  // Workspace (~81 MB of the budget):
  //  [0,    EH) binput8 e4m3 (dead after M6; atomh bf16 = NATOMS*H*2 = EH overlays)
  //  [EH,  2EH) QA payload | [2EH, 3EH) QB payload
  //  [3EH, ...) SA scales (1.6MB) | SB scales (1.6MB)
  char* W = (char*)d_ws;
  u8*    binput8 = (u8*)W;
  u8*    QA = (u8*)(W + EH);
  u8*    QB = (u8*)(W + 2 * EH);
  bf16s* SA = (bf16s*)(W + 3 * EH);
  bf16s* SB = (bf16s*)(W + 3 * EH + (size_t)EDGES * 8);
  bf16s* atomh = (bf16s*)W;
  bf16s* wt_h = (bf16s*)d_out;   // stashed in d_out; k_pool overwrites later
  bf16s* wt_o = wt_h + H * H;
  bf16s* wt_i = wt_o + H * H;

  k_wt<<<3, 256, 0, stream>>>(Wh, Wo, Wi, wt_h, wt_o, wt_i);
  k_binput_gemm<<<EDGES / 64, 256, 0, stream>>>(fbonds, wt_i, wt_h, binput8, QA, SA); // M1
  k_fusedq<<<EDGES / 32, 128, 0, stream>>>(bgraph, QA, SA, binput8, wt_h, QB, SB);    // M2
  k_fusedq<<<EDGES / 32, 128, 0, stream>>>(bgraph, QB, SB, binput8, wt_h, QA, SA);    // M3
  k_fusedq<<<EDGES / 32, 128, 0, stream>>>(bgraph, QA, SA, binput8, wt_h, QB, SB);    // M4
  k_fusedq<<<EDGES / 32, 128, 0, stream>>>(bgraph, QB, SB, binput8, wt_h, QA, SA);    // M5
  k_fusedq<<<EDGES / 32, 128, 0, stream>>>(bgraph, QA, SA, binput8, wt_o, QB, SB);    // M6
  k_atoms<<<NATOMS / 32, 256, 0, stream>>>(fatoms, agraph, QB, SB, Wo, bo, atomh);
  k_pool<<<NMOLS, H, 0, stream>>>(atomh, sstart, slen, out);
}